// Round 5
// baseline (322.144 us; speedup 1.0000x reference)
//
#include <hip/hip_runtime.h>
#include <math.h>

namespace {
constexpr int NB = 512;
constexpr int NL = 50;
constexpr int NKN = 32;
constexpr int ND = 100;
constexpr int NV = 100000;
constexpr int NBL = NB * NL;          // 25600
constexpr int NVP = 100096;           // 782*128, padded V for Efrag
constexpr int NEB = 1564;             // prep_E blocks (64 rows each)
}

typedef __attribute__((ext_vector_type(8))) short bf16x8;
typedef __attribute__((ext_vector_type(4))) short short4v;
typedef __attribute__((ext_vector_type(8))) short short8v;
typedef __attribute__((ext_vector_type(4))) float f32x4;

__device__ inline unsigned short f2bf(float x) {
    unsigned u = __float_as_uint(x);
    unsigned r = (u + 0x7fffu + ((u >> 16) & 1u)) >> 16;
    return (unsigned short)r;
}
__device__ inline float bf2f(unsigned short h) {
    return __uint_as_float(((unsigned)h) << 16);
}

// ---------------------------------------------------------------------------
// prep_E: E_tag -> bf16 MFMA B-fragments Efrag[kg 0..15][NVP][8]
//         (k = kg*8+j, zero for k>=100 and rows >= NV)
//         + per-block column-sum partials for ebar.
// ---------------------------------------------------------------------------
__global__ __launch_bounds__(256) void prep_E(
    const float* __restrict__ E_tag,
    unsigned short* __restrict__ Efrag,
    float* __restrict__ partial)          // [NEB][100]
{
    __shared__ float es[64][100];
    const int tid = threadIdx.x;
    const int blk = blockIdx.x;
    const int v0  = blk * 64;

    for (int idx = tid; idx < 1600; idx += 256) {
        size_t base = (size_t)v0 * 100 + (size_t)idx * 4;
        float4 e = make_float4(0.f, 0.f, 0.f, 0.f);
        if (base + 3 < (size_t)NV * ND) e = *(const float4*)(E_tag + base);
        int row = idx / 25, c4 = (idx - row * 25) * 4;
        es[row][c4]     = e.x;
        es[row][c4 + 1] = e.y;
        es[row][c4 + 2] = e.z;
        es[row][c4 + 3] = e.w;
    }
    __syncthreads();

    if (tid < ND) {
        float a = 0.f;
#pragma unroll 8
        for (int rr = 0; rr < 64; ++rr) a += es[rr][tid];
        partial[blk * ND + tid] = a;
    }

    // fragment writes: idx = kg*64 + vloc (vloc fastest -> coalesced 16B)
    for (int idx = tid; idx < 16 * 64; idx += 256) {
        int kg = idx >> 6, vloc = idx & 63;
        short8v o;
#pragma unroll
        for (int j = 0; j < 8; ++j) {
            int k = kg * 8 + j;
            o[j] = (short)((k < ND) ? f2bf(es[vloc][k]) : 0);
        }
        *(short8v*)(Efrag + ((size_t)kg * NVP + v0 + vloc) * 8) = o;
    }
}

__global__ __launch_bounds__(128) void ebar_final(const float* __restrict__ partial,
                                                  float* __restrict__ ebar)
{
    int tid = threadIdx.x;
    if (tid < ND) {
        float a = 0.f;
#pragma unroll 4
        for (int i = 0; i < NEB; ++i) a += partial[i * ND + tid];
        ebar[tid] = a * (1.f / (float)NV);
    }
}

// ---------------------------------------------------------------------------
// prep_A: A fragments for gates GEMM.  seg = kg>>4: 0->u, 1->v, 2->x.
// ---------------------------------------------------------------------------
__global__ __launch_bounds__(256) void prep_A(
    const int* __restrict__ seq, const int* __restrict__ lens,
    const float* __restrict__ E_ggnn, unsigned short* __restrict__ Afrag)
{
    __shared__ float xs[34][100];
    __shared__ float eo_s[34], ei_s[34];
    const int tid = threadIdx.x;
    const int r0  = blockIdx.x * 32;

    for (int idx = tid; idx < 34 * 25; idx += 256) {
        int row = idx / 25, qq = idx - row * 25;
        int rg = r0 - 1 + row;
        rg = rg < 0 ? 0 : (rg >= NBL ? NBL - 1 : rg);
        float4 e = *(const float4*)(E_ggnn + (size_t)seq[rg] * ND + 4 * qq);
        xs[row][4 * qq]     = e.x;
        xs[row][4 * qq + 1] = e.y;
        xs[row][4 * qq + 2] = e.z;
        xs[row][4 * qq + 3] = e.w;
    }
    for (int rr = tid; rr < 34; rr += 256) {
        int rg = r0 - 1 + rr;
        int rc = rg < 0 ? 0 : (rg >= NBL ? NBL - 1 : rg);
        int b = rc / NL, l = rc - b * NL;
        int lenb = lens[b];
        eo_s[rr] = (l < lenb - 1) ? 1.f : 0.f;
        ei_s[rr] = (l >= 1 && l <= lenb - 1) ? 1.f : 0.f;
    }
    __syncthreads();

    for (int idx = tid; idx < 32 * 48; idx += 256) {
        int rloc = idx / 48, kg = idx - rloc * 48;
        int seg = kg >> 4, kk = kg & 15;
        short8v o;
        float eo = eo_s[1 + rloc], ei = ei_s[1 + rloc];
#pragma unroll
        for (int j = 0; j < 8; ++j) {
            int k = kk * 8 + j;
            float v = 0.f;
            if (k < 100) {
                if (seg == 0)      v = xs[1 + rloc][k] + eo * xs[2 + rloc][k];
                else if (seg == 1) v = xs[1 + rloc][k] + ei * xs[rloc][k];
                else               v = xs[1 + rloc][k];
            }
            o[j] = (short)f2bf(v);
        }
        *(short8v*)(Afrag + ((size_t)kg * NBL + r0 + rloc) * 8) = o;
    }
}

// ---------------------------------------------------------------------------
// prep_B: Bfrag[kg][col 0..639][8] bf16.
// ---------------------------------------------------------------------------
__global__ __launch_bounds__(256) void prep_B(
    const float* __restrict__ W_ih, const float* __restrict__ W_hh,
    unsigned short* __restrict__ Bfrag)
{
    int idx = blockIdx.x * 256 + threadIdx.x;   // (kg, col)
    if (idx >= 48 * 640) return;
    int kg = idx / 640, col = idx - kg * 640;
    int seg = kg >> 4, kk = kg & 15;
    short8v o;
#pragma unroll
    for (int j = 0; j < 8; ++j) {
        int k = kk * 8 + j;
        float v = 0.f;
        if (k < 100) {
            if (seg == 0 && col < 300)                 v = W_ih[k * 300 + col];
            else if (seg == 1 && col < 300)            v = W_ih[(100 + k) * 300 + col];
            else if (seg == 2 && col >= 300 && col < 600) v = W_hh[k * 300 + (col - 300)];
        }
        o[j] = (short)f2bf(v);
    }
    *(short8v*)(Bfrag + (size_t)idx * 8) = o;
}

// ---------------------------------------------------------------------------
// K1: gates GEMM via MFMA bf16.  Output G in bf16.
// ---------------------------------------------------------------------------
__global__ __launch_bounds__(256) void gates_mfma(
    const unsigned short* __restrict__ Afrag,
    const unsigned short* __restrict__ Bfrag,
    unsigned short* __restrict__ G)
{
    const int tid = threadIdx.x;
    const int r0  = blockIdx.x * 128;
    const int v0  = blockIdx.y * 128;
    const int lane = tid & 63;
    const int wv = tid >> 6;
    const int wm = wv >> 1, wn = wv & 1;
    const int q = lane >> 4, c = lane & 15;

    f32x4 acc[4][4];
#pragma unroll
    for (int fm = 0; fm < 4; ++fm)
#pragma unroll
        for (int fn = 0; fn < 4; ++fn) acc[fm][fn] = (f32x4)0.f;

    const bf16x8* Ap = (const bf16x8*)Afrag;
    const bf16x8* Bp = (const bf16x8*)Bfrag;

#pragma unroll
    for (int s = 0; s < 12; ++s) {
        const int kg = 4 * s + q;
        bf16x8 a[4], b[4];
#pragma unroll
        for (int fm = 0; fm < 4; ++fm)
            a[fm] = Ap[(size_t)kg * NBL + r0 + wm * 64 + fm * 16 + c];
#pragma unroll
        for (int fn = 0; fn < 4; ++fn)
            b[fn] = Bp[(size_t)kg * 640 + v0 + wn * 64 + fn * 16 + c];
#pragma unroll
        for (int fm = 0; fm < 4; ++fm)
#pragma unroll
            for (int fn = 0; fn < 4; ++fn)
                acc[fm][fn] = __builtin_amdgcn_mfma_f32_16x16x32_bf16(
                    a[fm], b[fn], acc[fm][fn], 0, 0, 0);
    }

#pragma unroll
    for (int fm = 0; fm < 4; ++fm) {
        int rb = r0 + wm * 64 + fm * 16 + q * 4;
#pragma unroll
        for (int fn = 0; fn < 4; ++fn) {
            int col = v0 + wn * 64 + fn * 16 + c;
            if (col < 600) {
#pragma unroll
                for (int r = 0; r < 4; ++r)
                    G[(size_t)(rb + r) * 600 + col] = f2bf(acc[fm][fn][r]);
            }
        }
    }
}

// ---------------------------------------------------------------------------
// K2: GRU elementwise (G in bf16)
// ---------------------------------------------------------------------------
__global__ __launch_bounds__(256) void gru2(
    const int* __restrict__ seq, const float* __restrict__ E_ggnn,
    const unsigned short* __restrict__ G,
    const float* __restrict__ b_ih, const float* __restrict__ b_hh,
    float* __restrict__ h0)
{
    int idx = blockIdx.x * 256 + threadIdx.x;
    if (idx >= NBL * ND) return;
    int r = idx / ND, d = idx - r * ND;
    const unsigned short* Gr = G + (size_t)r * 600;
    float ir = bf2f(Gr[d])       + b_ih[d];
    float iz = bf2f(Gr[100 + d]) + b_ih[100 + d];
    float ig = bf2f(Gr[200 + d]) + b_ih[200 + d];
    float hr = bf2f(Gr[300 + d]) + b_hh[d];
    float hz = bf2f(Gr[400 + d]) + b_hh[100 + d];
    float hg = bf2f(Gr[500 + d]) + b_hh[200 + d];
    float x  = E_ggnn[(size_t)seq[r] * ND + d];
    float rg = 1.f / (1.f + expf(-(ir + hr)));
    float zg = 1.f / (1.f + expf(-(iz + hz)));
    float ng = tanhf(ig + rg * hg);
    h0[idx] = (1.f - zg) * ng + zg * x;
}

// ---------------------------------------------------------------------------
// K45: per-batch fused tail -> sess2 bf16 fragments A[kg 0..15][512][8]
// ---------------------------------------------------------------------------
__global__ __launch_bounds__(128) void fuse_kernel(
    const int* __restrict__ seq, const int* __restrict__ lens,
    const int* __restrict__ nei, const float* __restrict__ wei,
    const float* __restrict__ s_vec, const float* __restrict__ E_tag,
    const float* __restrict__ E_glob,
    const float* __restrict__ Wout_w, const float* __restrict__ Wout_b,
    const float* __restrict__ W_w,
    const float* __restrict__ W3_w, const float* __restrict__ W3_b,
    const float* __restrict__ W1_w, const float* __restrict__ W1_b,
    const float* __restrict__ q1_w,
    const float* __restrict__ W2_w, const float* __restrict__ W2_b,
    const float* __restrict__ G1_w, const float* __restrict__ G1_b,
    const float* __restrict__ G2_w, const float* __restrict__ G2_b,
    const float* __restrict__ ebar, const float* __restrict__ h0,
    unsigned short* __restrict__ A_hi)
{
    const int b = blockIdx.x, tid = threadIdx.x;
    __shared__ float t_emb[100], tw[100], twW[100], red[128];
    __shared__ float al[50], att[50];
    __shared__ float g0[100], cc[300], sess_s[100];
    __shared__ float sv[100], hnei[32][100], msg[100], xg[100], xg2[100];
    __shared__ float attg[32], score[32];
    __shared__ float scalars[4];      // 0: bd, 1: sm, 2: mean_b, 3: gate

    int lenb   = lens[b];
    int last_r = b * NL + (lenb - 1);
    int target = seq[last_r];

    if (tid < ND) {
        t_emb[tid] = E_tag[(size_t)target * ND + tid];
        sv[tid]    = s_vec[b * ND + tid];
    }
    __syncthreads();

    if (tid < ND) {
        float a = 0.f;
        for (int k = 0; k < ND; ++k) a += t_emb[k] * W_w[k * ND + tid];
        tw[tid] = a;
    }
    __syncthreads();

    if (tid < ND) {
        float a = 0.f;
        for (int d = 0; d < ND; ++d) a += Wout_w[tid * ND + d] * tw[d];
        twW[tid] = a;
    }
    red[tid] = (tid < ND) ? Wout_b[tid] * tw[tid] : 0.f;
    __syncthreads();
    for (int s = 64; s > 0; s >>= 1) { if (tid < s) red[tid] += red[tid + s]; __syncthreads(); }
    if (tid == 0) scalars[0] = red[0];
    __syncthreads();

    if (tid < NL) {
        const float* hr = h0 + (size_t)(b * NL + tid) * ND;
        float a = scalars[0];
        for (int k = 0; k < ND; ++k) a += hr[k] * twW[k];
        al[tid] = a;
    }
    __syncthreads();
    if (tid == 0) {
        float m = -1e30f;
        for (int l = 0; l < NL; ++l) m = fmaxf(m, al[l]);
        float s = 0.f;
        for (int l = 0; l < NL; ++l) { float e = expf(al[l] - m); att[l] = e; s += e; }
        float inv = 1.f / s, sm = 0.f;
        for (int l = 0; l < NL; ++l) { att[l] *= inv; if (l < lenb) sm += att[l]; }
        scalars[1] = sm;
    }
    __syncthreads();

    if (tid < ND) {
        float a = 0.f;
        for (int l = 0; l < lenb; ++l) a += att[l] * h0[(size_t)(b * NL + l) * ND + tid];
        g0[tid] = a;
    }
    __syncthreads();
    if (tid < ND) {
        float hg = 0.f, hl = 0.f;
        const float* hlast = h0 + (size_t)last_r * ND;
        for (int k = 0; k < ND; ++k) {
            float w = Wout_w[k * ND + tid];
            hg += g0[k] * w;
            hl += hlast[k] * w;
        }
        cc[tid]        = hg + scalars[1] * Wout_b[tid];
        cc[100 + tid]  = hl + Wout_b[tid];
        cc[200 + tid]  = t_emb[tid];
    }
    __syncthreads();

    if (tid < ND) {
        float a = W3_b[tid];
        for (int j = 0; j < 300; ++j) a += cc[j] * W3_w[j * ND + tid];
        sess_s[tid] = tanhf(a);
    }
    __syncthreads();
    red[tid] = (tid < ND) ? sess_s[tid] * ebar[tid] : 0.f;
    __syncthreads();
    for (int s = 64; s > 0; s >>= 1) { if (tid < s) red[tid] += red[tid + s]; __syncthreads(); }
    if (tid == 0) scalars[2] = red[0];
    __syncthreads();

    // ---- global encoder ----
    for (int idx = tid; idx < NKN * ND; idx += 128) {
        int k = idx / ND, d = idx - k * ND;
        hnei[k][d] = E_glob[(size_t)nei[b * NKN + k] * ND + d];
    }
    __syncthreads();

    {
        const int wv = tid >> 6, lane = tid & 63;
        for (int k2 = 0; k2 < NKN / 2; ++k2) {
            int k = k2 * 2 + wv;
            float p = 0.f;
            if (lane < 50) {
                float wk = wei[b * NKN + k];
                float a0 = W1_b[lane]      + wk * W1_w[100 * ND + lane];
                float a1 = W1_b[lane + 50] + wk * W1_w[100 * ND + lane + 50];
                for (int j = 0; j < ND; ++j) {
                    float t = hnei[k][j] * sv[j];
                    a0 += t * W1_w[j * ND + lane];
                    a1 += t * W1_w[j * ND + lane + 50];
                }
                p = tanhf(a0) * q1_w[lane] + tanhf(a1) * q1_w[lane + 50];
            }
            for (int off = 32; off > 0; off >>= 1) p += __shfl_down(p, off);
            if (lane == 0) score[k] = p;
        }
    }
    __syncthreads();

    if (tid == 0) {
        float m = -1e30f;
        for (int k = 0; k < NKN; ++k) m = fmaxf(m, score[k]);
        float s = 0.f;
        for (int k = 0; k < NKN; ++k) { float e = expf(score[k] - m); attg[k] = e; s += e; }
        float inv = 1.f / s;
        for (int k = 0; k < NKN; ++k) attg[k] *= inv;
    }
    __syncthreads();
    if (tid < ND) {
        float a = 0.f;
        for (int k = 0; k < NKN; ++k) a += attg[k] * hnei[k][tid];
        msg[tid] = a;
        xg[tid]  = E_glob[(size_t)target * ND + tid];
    }
    __syncthreads();
    if (tid < ND) {
        float a = W2_b[tid];
        for (int j = 0; j < ND; ++j) a += xg[j]  * W2_w[j * ND + tid];
        for (int j = 0; j < ND; ++j) a += msg[j] * W2_w[(100 + j) * ND + tid];
        xg2[tid] = fmaxf(a, 0.f);
    }
    __syncthreads();
    const float SCALE = (float)(1.0 - 49.0 / 50.0);
    if (tid < ND) {
        float a = W2_b[tid];
        for (int j = 0; j < ND; ++j) a += xg2[j] * W2_w[j * ND + tid];
        for (int j = 0; j < ND; ++j) a += msg[j] * W2_w[(100 + j) * ND + tid];
        xg[tid] = fmaxf(a, 0.f) * SCALE;
    }
    __syncthreads();

    if (tid < ND) {
        float a = G1_b[tid] + scalars[2] * G1_w[tid];
        for (int j = 0; j < ND; ++j) a += xg[j] * G1_w[(1 + j) * ND + tid];
        red[tid] = tanhf(a) * G2_w[tid];
    } else red[tid] = 0.f;
    __syncthreads();
    for (int s = 64; s > 0; s >>= 1) { if (tid < s) red[tid] += red[tid + s]; __syncthreads(); }
    if (tid == 0) scalars[3] = 1.f / (1.f + expf(-(red[0] + G2_b[0])));
    __syncthreads();

    {
        float val = 0.f;
        if (tid < ND) {
            float g = scalars[3];
            val = g * xg[tid] + (1.f - g) * scalars[2];
        }
        int kgrp = tid >> 3, j = tid & 7;
        A_hi[kgrp * 4096 + b * 8 + j] = f2bf(val);
    }
}

// ---------------------------------------------------------------------------
// K6: out = sess2 @ E_tag^T, streaming MFMA: no LDS, frags from global.
//     BM=128 x BN=128, 4 waves, Kp=128 (kg 12..15 mostly zero).
// ---------------------------------------------------------------------------
__global__ __launch_bounds__(256) void out_gemm_mfma(
    const unsigned short* __restrict__ A_hi,
    const unsigned short* __restrict__ Efrag,
    float* __restrict__ out)
{
    const int tid = threadIdx.x;
    const int v0  = blockIdx.x * 128;
    const int b0  = blockIdx.y * 128;
    const int lane = tid & 63;
    const int wv = tid >> 6;
    const int wm = wv >> 1, wn = wv & 1;
    const int q = lane >> 4, c = lane & 15;

    f32x4 acc[4][4];
#pragma unroll
    for (int fm = 0; fm < 4; ++fm)
#pragma unroll
        for (int fn = 0; fn < 4; ++fn) acc[fm][fn] = (f32x4)0.f;

    const bf16x8* Ah = (const bf16x8*)A_hi;
    const bf16x8* Ef = (const bf16x8*)Efrag;

#pragma unroll
    for (int s = 0; s < 4; ++s) {
        const int kg = 4 * s + q;
        bf16x8 a[4], b[4];
#pragma unroll
        for (int fm = 0; fm < 4; ++fm)
            a[fm] = Ah[kg * 512 + b0 + wm * 64 + fm * 16 + c];
#pragma unroll
        for (int fn = 0; fn < 4; ++fn)
            b[fn] = Ef[(size_t)kg * NVP + v0 + wn * 64 + fn * 16 + c];
#pragma unroll
        for (int fm = 0; fm < 4; ++fm)
#pragma unroll
            for (int fn = 0; fn < 4; ++fn)
                acc[fm][fn] = __builtin_amdgcn_mfma_f32_16x16x32_bf16(
                    a[fm], b[fn], acc[fm][fn], 0, 0, 0);
    }

#pragma unroll
    for (int fm = 0; fm < 4; ++fm) {
        int row_base = b0 + wm * 64 + fm * 16 + q * 4;
#pragma unroll
        for (int fn = 0; fn < 4; ++fn) {
            int col = v0 + wn * 64 + fn * 16 + c;
            if (col < NV) {
#pragma unroll
                for (int r = 0; r < 4; ++r)
                    out[(size_t)(row_base + r) * NV + col] = acc[fm][fn][r];
            }
        }
    }
}

// ---------------------------------------------------------------------------
extern "C" void kernel_launch(void* const* d_in, const int* in_sizes, int n_in,
                              void* d_out, int out_size, void* d_ws, size_t ws_size,
                              hipStream_t stream)
{
    const int*   seq    = (const int*)  d_in[0];
    const int*   lens   = (const int*)  d_in[1];
    const int*   nei    = (const int*)  d_in[2];
    const float* wei    = (const float*)d_in[3];
    const float* s_vec  = (const float*)d_in[4];
    const float* E_tag  = (const float*)d_in[5];
    const float* E_ggnn = (const float*)d_in[6];
    const float* E_glob = (const float*)d_in[7];
    const float* W_ih   = (const float*)d_in[8];
    const float* b_ih   = (const float*)d_in[9];
    const float* W_hh   = (const float*)d_in[10];
    const float* b_hh   = (const float*)d_in[11];
    const float* Wout_w = (const float*)d_in[12];
    const float* Wout_b = (const float*)d_in[13];
    const float* W_w    = (const float*)d_in[14];
    const float* W3_w   = (const float*)d_in[15];
    const float* W3_b   = (const float*)d_in[16];
    const float* W1_w   = (const float*)d_in[17];
    const float* W1_b   = (const float*)d_in[18];
    const float* q1_w   = (const float*)d_in[19];
    const float* W2_w   = (const float*)d_in[20];
    const float* W2_b   = (const float*)d_in[21];
    const float* G1_w   = (const float*)d_in[22];
    const float* G1_b   = (const float*)d_in[23];
    const float* G2_w   = (const float*)d_in[24];
    const float* G2_b   = (const float*)d_in[25];

    float* out = (float*)d_out;
    // d_out staging (all consumed before out_gemm writes):
    //   G bf16   [0 .. 7.68M floats)
    //   Afrag    at float-offset 16M (48*25600*8 ushorts)
    //   Bfrag    at float-offset 21M (48*640*8 ushorts)
    unsigned short* Gm    = (unsigned short*)out;
    unsigned short* Afrag = (unsigned short*)(out + 16000000);
    unsigned short* Bfrag = (unsigned short*)(out + 21000000);

    // d_ws layout (floats):
    float* ws      = (float*)d_ws;
    float* h0      = ws;                            // 2.56M
    float* partial = ws + 2560000;                  // NEB*100 = 156.4K
    float* ebar    = ws + 2720000;                  // 128
    unsigned short* A_hi  = (unsigned short*)(ws + 2724000);   // 65536 ushorts
    unsigned short* Efrag = (unsigned short*)(ws + 3000000);   // 16*NVP*8 ushorts

    prep_E<<<NEB, 256, 0, stream>>>(E_tag, Efrag, partial);
    ebar_final<<<1, 128, 0, stream>>>(partial, ebar);
    prep_A<<<NBL / 32, 256, 0, stream>>>(seq, lens, E_ggnn, Afrag);
    prep_B<<<(48 * 640 + 255) / 256, 256, 0, stream>>>(W_ih, W_hh, Bfrag);
    gates_mfma<<<dim3(NBL / 128, 5), 256, 0, stream>>>(Afrag, Bfrag, Gm);
    gru2<<<(NBL * ND + 255) / 256, 256, 0, stream>>>(seq, E_ggnn, Gm, b_ih, b_hh, h0);
    fuse_kernel<<<NB, 128, 0, stream>>>(seq, lens, nei, wei, s_vec, E_tag, E_glob,
                                        Wout_w, Wout_b, W_w, W3_w, W3_b,
                                        W1_w, W1_b, q1_w, W2_w, W2_b,
                                        G1_w, G1_b, G2_w, G2_b, ebar, h0, A_hi);
    out_gemm_mfma<<<dim3(NVP / 128, NB / 128), 256, 0, stream>>>(A_hi, Efrag, out);
}

// Round 6
// 220.315 us; speedup vs baseline: 1.4622x; 1.4622x over previous
//
#include <hip/hip_runtime.h>
#include <math.h>

namespace {
constexpr int NB = 512;
constexpr int NL = 50;
constexpr int NKN = 32;
constexpr int ND = 100;
constexpr int NV = 100000;
constexpr int NBL = NB * NL;          // 25600
constexpr int NVP = 100096;           // 782*128, padded V for Efrag
constexpr int NEB = 1564;             // prep_E blocks (64 rows each)
}

typedef __attribute__((ext_vector_type(8))) short bf16x8;
typedef __attribute__((ext_vector_type(4))) short short4v;
typedef __attribute__((ext_vector_type(8))) short short8v;
typedef __attribute__((ext_vector_type(4))) float f32x4;

__device__ inline unsigned short f2bf(float x) {
    unsigned u = __float_as_uint(x);
    unsigned r = (u + 0x7fffu + ((u >> 16) & 1u)) >> 16;
    return (unsigned short)r;
}
__device__ inline float bf2f(unsigned short h) {
    return __uint_as_float(((unsigned)h) << 16);
}

// ---------------------------------------------------------------------------
// prep_E: E_tag -> bf16 MFMA B-fragments Efrag[kg 0..15][NVP][8]
//         (k = kg*8+j, zero for k>=100 and rows >= NV)
//         + per-block column-sum partials, written TRANSPOSED partialT[d][blk]
//         so ebar_final can reduce coalesced in parallel.
// ---------------------------------------------------------------------------
__global__ __launch_bounds__(256) void prep_E(
    const float* __restrict__ E_tag,
    unsigned short* __restrict__ Efrag,
    float* __restrict__ partialT)         // [100][NEB]
{
    __shared__ float es[64][100];
    const int tid = threadIdx.x;
    const int blk = blockIdx.x;
    const int v0  = blk * 64;

    for (int idx = tid; idx < 1600; idx += 256) {
        size_t base = (size_t)v0 * 100 + (size_t)idx * 4;
        float4 e = make_float4(0.f, 0.f, 0.f, 0.f);
        if (base + 3 < (size_t)NV * ND) e = *(const float4*)(E_tag + base);
        int row = idx / 25, c4 = (idx - row * 25) * 4;
        es[row][c4]     = e.x;
        es[row][c4 + 1] = e.y;
        es[row][c4 + 2] = e.z;
        es[row][c4 + 3] = e.w;
    }
    __syncthreads();

    if (tid < ND) {
        float a = 0.f;
#pragma unroll 8
        for (int rr = 0; rr < 64; ++rr) a += es[rr][tid];
        partialT[(size_t)tid * NEB + blk] = a;
    }

    // fragment writes: idx = kg*64 + vloc (vloc fastest -> coalesced 16B)
    for (int idx = tid; idx < 16 * 64; idx += 256) {
        int kg = idx >> 6, vloc = idx & 63;
        short8v o;
#pragma unroll
        for (int j = 0; j < 8; ++j) {
            int k = kg * 8 + j;
            o[j] = (short)((k < ND) ? f2bf(es[vloc][k]) : 0);
        }
        *(short8v*)(Efrag + ((size_t)kg * NVP + v0 + vloc) * 8) = o;
    }
}

// ebar_final v2: one block per column d, coalesced strip reduce.
__global__ __launch_bounds__(256) void ebar_final(const float* __restrict__ partialT,
                                                  float* __restrict__ ebar)
{
    const int d = blockIdx.x;             // 0..99
    const int tid = threadIdx.x;
    float a = 0.f;
    for (int i = tid; i < NEB; i += 256) a += partialT[(size_t)d * NEB + i];
#pragma unroll
    for (int off = 32; off > 0; off >>= 1) a += __shfl_down(a, off);
    __shared__ float wsum[4];
    if ((tid & 63) == 0) wsum[tid >> 6] = a;
    __syncthreads();
    if (tid == 0)
        ebar[d] = (wsum[0] + wsum[1] + wsum[2] + wsum[3]) * (1.f / (float)NV);
}

// ---------------------------------------------------------------------------
// prep_A: A fragments for gates GEMM.  seg = kg>>4: 0->u, 1->v, 2->x.
// ---------------------------------------------------------------------------
__global__ __launch_bounds__(256) void prep_A(
    const int* __restrict__ seq, const int* __restrict__ lens,
    const float* __restrict__ E_ggnn, unsigned short* __restrict__ Afrag)
{
    __shared__ float xs[34][100];
    __shared__ float eo_s[34], ei_s[34];
    const int tid = threadIdx.x;
    const int r0  = blockIdx.x * 32;

    for (int idx = tid; idx < 34 * 25; idx += 256) {
        int row = idx / 25, qq = idx - row * 25;
        int rg = r0 - 1 + row;
        rg = rg < 0 ? 0 : (rg >= NBL ? NBL - 1 : rg);
        float4 e = *(const float4*)(E_ggnn + (size_t)seq[rg] * ND + 4 * qq);
        xs[row][4 * qq]     = e.x;
        xs[row][4 * qq + 1] = e.y;
        xs[row][4 * qq + 2] = e.z;
        xs[row][4 * qq + 3] = e.w;
    }
    for (int rr = tid; rr < 34; rr += 256) {
        int rg = r0 - 1 + rr;
        int rc = rg < 0 ? 0 : (rg >= NBL ? NBL - 1 : rg);
        int b = rc / NL, l = rc - b * NL;
        int lenb = lens[b];
        eo_s[rr] = (l < lenb - 1) ? 1.f : 0.f;
        ei_s[rr] = (l >= 1 && l <= lenb - 1) ? 1.f : 0.f;
    }
    __syncthreads();

    for (int idx = tid; idx < 32 * 48; idx += 256) {
        int rloc = idx / 48, kg = idx - rloc * 48;
        int seg = kg >> 4, kk = kg & 15;
        short8v o;
        float eo = eo_s[1 + rloc], ei = ei_s[1 + rloc];
#pragma unroll
        for (int j = 0; j < 8; ++j) {
            int k = kk * 8 + j;
            float v = 0.f;
            if (k < 100) {
                if (seg == 0)      v = xs[1 + rloc][k] + eo * xs[2 + rloc][k];
                else if (seg == 1) v = xs[1 + rloc][k] + ei * xs[rloc][k];
                else               v = xs[1 + rloc][k];
            }
            o[j] = (short)f2bf(v);
        }
        *(short8v*)(Afrag + ((size_t)kg * NBL + r0 + rloc) * 8) = o;
    }
}

// ---------------------------------------------------------------------------
// prep_B: Bfrag[kg][col 0..639][8] bf16.
// ---------------------------------------------------------------------------
__global__ __launch_bounds__(256) void prep_B(
    const float* __restrict__ W_ih, const float* __restrict__ W_hh,
    unsigned short* __restrict__ Bfrag)
{
    int idx = blockIdx.x * 256 + threadIdx.x;   // (kg, col)
    if (idx >= 48 * 640) return;
    int kg = idx / 640, col = idx - kg * 640;
    int seg = kg >> 4, kk = kg & 15;
    short8v o;
#pragma unroll
    for (int j = 0; j < 8; ++j) {
        int k = kk * 8 + j;
        float v = 0.f;
        if (k < 100) {
            if (seg == 0 && col < 300)                 v = W_ih[k * 300 + col];
            else if (seg == 1 && col < 300)            v = W_ih[(100 + k) * 300 + col];
            else if (seg == 2 && col >= 300 && col < 600) v = W_hh[k * 300 + (col - 300)];
        }
        o[j] = (short)f2bf(v);
    }
    *(short8v*)(Bfrag + (size_t)idx * 8) = o;
}

// ---------------------------------------------------------------------------
// K1: gates GEMM via MFMA bf16.  Output G in bf16.
// ---------------------------------------------------------------------------
__global__ __launch_bounds__(256) void gates_mfma(
    const unsigned short* __restrict__ Afrag,
    const unsigned short* __restrict__ Bfrag,
    unsigned short* __restrict__ G)
{
    const int tid = threadIdx.x;
    const int r0  = blockIdx.x * 128;
    const int v0  = blockIdx.y * 128;
    const int lane = tid & 63;
    const int wv = tid >> 6;
    const int wm = wv >> 1, wn = wv & 1;
    const int q = lane >> 4, c = lane & 15;

    f32x4 acc[4][4];
#pragma unroll
    for (int fm = 0; fm < 4; ++fm)
#pragma unroll
        for (int fn = 0; fn < 4; ++fn) acc[fm][fn] = (f32x4)0.f;

    const bf16x8* Ap = (const bf16x8*)Afrag;
    const bf16x8* Bp = (const bf16x8*)Bfrag;

#pragma unroll
    for (int s = 0; s < 12; ++s) {
        const int kg = 4 * s + q;
        bf16x8 a[4], b[4];
#pragma unroll
        for (int fm = 0; fm < 4; ++fm)
            a[fm] = Ap[(size_t)kg * NBL + r0 + wm * 64 + fm * 16 + c];
#pragma unroll
        for (int fn = 0; fn < 4; ++fn)
            b[fn] = Bp[(size_t)kg * 640 + v0 + wn * 64 + fn * 16 + c];
#pragma unroll
        for (int fm = 0; fm < 4; ++fm)
#pragma unroll
            for (int fn = 0; fn < 4; ++fn)
                acc[fm][fn] = __builtin_amdgcn_mfma_f32_16x16x32_bf16(
                    a[fm], b[fn], acc[fm][fn], 0, 0, 0);
    }

#pragma unroll
    for (int fm = 0; fm < 4; ++fm) {
        int rb = r0 + wm * 64 + fm * 16 + q * 4;
#pragma unroll
        for (int fn = 0; fn < 4; ++fn) {
            int col = v0 + wn * 64 + fn * 16 + c;
            if (col < 600) {
#pragma unroll
                for (int r = 0; r < 4; ++r)
                    G[(size_t)(rb + r) * 600 + col] = f2bf(acc[fm][fn][r]);
            }
        }
    }
}

// ---------------------------------------------------------------------------
// K2: GRU elementwise (G in bf16)
// ---------------------------------------------------------------------------
__global__ __launch_bounds__(256) void gru2(
    const int* __restrict__ seq, const float* __restrict__ E_ggnn,
    const unsigned short* __restrict__ G,
    const float* __restrict__ b_ih, const float* __restrict__ b_hh,
    float* __restrict__ h0)
{
    int idx = blockIdx.x * 256 + threadIdx.x;
    if (idx >= NBL * ND) return;
    int r = idx / ND, d = idx - r * ND;
    const unsigned short* Gr = G + (size_t)r * 600;
    float ir = bf2f(Gr[d])       + b_ih[d];
    float iz = bf2f(Gr[100 + d]) + b_ih[100 + d];
    float ig = bf2f(Gr[200 + d]) + b_ih[200 + d];
    float hr = bf2f(Gr[300 + d]) + b_hh[d];
    float hz = bf2f(Gr[400 + d]) + b_hh[100 + d];
    float hg = bf2f(Gr[500 + d]) + b_hh[200 + d];
    float x  = E_ggnn[(size_t)seq[r] * ND + d];
    float rg = 1.f / (1.f + expf(-(ir + hr)));
    float zg = 1.f / (1.f + expf(-(iz + hz)));
    float ng = tanhf(ig + rg * hg);
    h0[idx] = (1.f - zg) * ng + zg * x;
}

// ---------------------------------------------------------------------------
// K45: per-batch fused tail -> sess2 bf16 fragments A[kg 0..15][512][8]
// ---------------------------------------------------------------------------
__global__ __launch_bounds__(128) void fuse_kernel(
    const int* __restrict__ seq, const int* __restrict__ lens,
    const int* __restrict__ nei, const float* __restrict__ wei,
    const float* __restrict__ s_vec, const float* __restrict__ E_tag,
    const float* __restrict__ E_glob,
    const float* __restrict__ Wout_w, const float* __restrict__ Wout_b,
    const float* __restrict__ W_w,
    const float* __restrict__ W3_w, const float* __restrict__ W3_b,
    const float* __restrict__ W1_w, const float* __restrict__ W1_b,
    const float* __restrict__ q1_w,
    const float* __restrict__ W2_w, const float* __restrict__ W2_b,
    const float* __restrict__ G1_w, const float* __restrict__ G1_b,
    const float* __restrict__ G2_w, const float* __restrict__ G2_b,
    const float* __restrict__ ebar, const float* __restrict__ h0,
    unsigned short* __restrict__ A_hi)
{
    const int b = blockIdx.x, tid = threadIdx.x;
    __shared__ float t_emb[100], tw[100], twW[100], red[128];
    __shared__ float al[50], att[50];
    __shared__ float g0[100], cc[300], sess_s[100];
    __shared__ float sv[100], hnei[32][100], msg[100], xg[100], xg2[100];
    __shared__ float attg[32], score[32];
    __shared__ float scalars[4];      // 0: bd, 1: sm, 2: mean_b, 3: gate

    int lenb   = lens[b];
    int last_r = b * NL + (lenb - 1);
    int target = seq[last_r];

    if (tid < ND) {
        t_emb[tid] = E_tag[(size_t)target * ND + tid];
        sv[tid]    = s_vec[b * ND + tid];
    }
    __syncthreads();

    if (tid < ND) {
        float a = 0.f;
        for (int k = 0; k < ND; ++k) a += t_emb[k] * W_w[k * ND + tid];
        tw[tid] = a;
    }
    __syncthreads();

    if (tid < ND) {
        float a = 0.f;
        for (int d = 0; d < ND; ++d) a += Wout_w[tid * ND + d] * tw[d];
        twW[tid] = a;
    }
    red[tid] = (tid < ND) ? Wout_b[tid] * tw[tid] : 0.f;
    __syncthreads();
    for (int s = 64; s > 0; s >>= 1) { if (tid < s) red[tid] += red[tid + s]; __syncthreads(); }
    if (tid == 0) scalars[0] = red[0];
    __syncthreads();

    if (tid < NL) {
        const float* hr = h0 + (size_t)(b * NL + tid) * ND;
        float a = scalars[0];
        for (int k = 0; k < ND; ++k) a += hr[k] * twW[k];
        al[tid] = a;
    }
    __syncthreads();
    if (tid == 0) {
        float m = -1e30f;
        for (int l = 0; l < NL; ++l) m = fmaxf(m, al[l]);
        float s = 0.f;
        for (int l = 0; l < NL; ++l) { float e = expf(al[l] - m); att[l] = e; s += e; }
        float inv = 1.f / s, sm = 0.f;
        for (int l = 0; l < NL; ++l) { att[l] *= inv; if (l < lenb) sm += att[l]; }
        scalars[1] = sm;
    }
    __syncthreads();

    if (tid < ND) {
        float a = 0.f;
        for (int l = 0; l < lenb; ++l) a += att[l] * h0[(size_t)(b * NL + l) * ND + tid];
        g0[tid] = a;
    }
    __syncthreads();
    if (tid < ND) {
        float hg = 0.f, hl = 0.f;
        const float* hlast = h0 + (size_t)last_r * ND;
        for (int k = 0; k < ND; ++k) {
            float w = Wout_w[k * ND + tid];
            hg += g0[k] * w;
            hl += hlast[k] * w;
        }
        cc[tid]        = hg + scalars[1] * Wout_b[tid];
        cc[100 + tid]  = hl + Wout_b[tid];
        cc[200 + tid]  = t_emb[tid];
    }
    __syncthreads();

    if (tid < ND) {
        float a = W3_b[tid];
        for (int j = 0; j < 300; ++j) a += cc[j] * W3_w[j * ND + tid];
        sess_s[tid] = tanhf(a);
    }
    __syncthreads();
    red[tid] = (tid < ND) ? sess_s[tid] * ebar[tid] : 0.f;
    __syncthreads();
    for (int s = 64; s > 0; s >>= 1) { if (tid < s) red[tid] += red[tid + s]; __syncthreads(); }
    if (tid == 0) scalars[2] = red[0];
    __syncthreads();

    // ---- global encoder ----
    for (int idx = tid; idx < NKN * ND; idx += 128) {
        int k = idx / ND, d = idx - k * ND;
        hnei[k][d] = E_glob[(size_t)nei[b * NKN + k] * ND + d];
    }
    __syncthreads();

    {
        const int wv = tid >> 6, lane = tid & 63;
        for (int k2 = 0; k2 < NKN / 2; ++k2) {
            int k = k2 * 2 + wv;
            float p = 0.f;
            if (lane < 50) {
                float wk = wei[b * NKN + k];
                float a0 = W1_b[lane]      + wk * W1_w[100 * ND + lane];
                float a1 = W1_b[lane + 50] + wk * W1_w[100 * ND + lane + 50];
                for (int j = 0; j < ND; ++j) {
                    float t = hnei[k][j] * sv[j];
                    a0 += t * W1_w[j * ND + lane];
                    a1 += t * W1_w[j * ND + lane + 50];
                }
                p = tanhf(a0) * q1_w[lane] + tanhf(a1) * q1_w[lane + 50];
            }
            for (int off = 32; off > 0; off >>= 1) p += __shfl_down(p, off);
            if (lane == 0) score[k] = p;
        }
    }
    __syncthreads();

    if (tid == 0) {
        float m = -1e30f;
        for (int k = 0; k < NKN; ++k) m = fmaxf(m, score[k]);
        float s = 0.f;
        for (int k = 0; k < NKN; ++k) { float e = expf(score[k] - m); attg[k] = e; s += e; }
        float inv = 1.f / s;
        for (int k = 0; k < NKN; ++k) attg[k] *= inv;
    }
    __syncthreads();
    if (tid < ND) {
        float a = 0.f;
        for (int k = 0; k < NKN; ++k) a += attg[k] * hnei[k][tid];
        msg[tid] = a;
        xg[tid]  = E_glob[(size_t)target * ND + tid];
    }
    __syncthreads();
    if (tid < ND) {
        float a = W2_b[tid];
        for (int j = 0; j < ND; ++j) a += xg[j]  * W2_w[j * ND + tid];
        for (int j = 0; j < ND; ++j) a += msg[j] * W2_w[(100 + j) * ND + tid];
        xg2[tid] = fmaxf(a, 0.f);
    }
    __syncthreads();
    const float SCALE = (float)(1.0 - 49.0 / 50.0);
    if (tid < ND) {
        float a = W2_b[tid];
        for (int j = 0; j < ND; ++j) a += xg2[j] * W2_w[j * ND + tid];
        for (int j = 0; j < ND; ++j) a += msg[j] * W2_w[(100 + j) * ND + tid];
        xg[tid] = fmaxf(a, 0.f) * SCALE;
    }
    __syncthreads();

    if (tid < ND) {
        float a = G1_b[tid] + scalars[2] * G1_w[tid];
        for (int j = 0; j < ND; ++j) a += xg[j] * G1_w[(1 + j) * ND + tid];
        red[tid] = tanhf(a) * G2_w[tid];
    } else red[tid] = 0.f;
    __syncthreads();
    for (int s = 64; s > 0; s >>= 1) { if (tid < s) red[tid] += red[tid + s]; __syncthreads(); }
    if (tid == 0) scalars[3] = 1.f / (1.f + expf(-(red[0] + G2_b[0])));
    __syncthreads();

    {
        float val = 0.f;
        if (tid < ND) {
            float g = scalars[3];
            val = g * xg[tid] + (1.f - g) * scalars[2];
        }
        int kgrp = tid >> 3, j = tid & 7;
        A_hi[kgrp * 4096 + b * 8 + j] = f2bf(val);
    }
}

// ---------------------------------------------------------------------------
// K6: out = sess2 @ E_tag^T, streaming MFMA: no LDS, frags from global.
//     BM=128 x BN=128, 4 waves, Kp=128 (kg 12..15 mostly zero).
// ---------------------------------------------------------------------------
__global__ __launch_bounds__(256) void out_gemm_mfma(
    const unsigned short* __restrict__ A_hi,
    const unsigned short* __restrict__ Efrag,
    float* __restrict__ out)
{
    const int tid = threadIdx.x;
    const int v0  = blockIdx.x * 128;
    const int b0  = blockIdx.y * 128;
    const int lane = tid & 63;
    const int wv = tid >> 6;
    const int wm = wv >> 1, wn = wv & 1;
    const int q = lane >> 4, c = lane & 15;

    f32x4 acc[4][4];
#pragma unroll
    for (int fm = 0; fm < 4; ++fm)
#pragma unroll
        for (int fn = 0; fn < 4; ++fn) acc[fm][fn] = (f32x4)0.f;

    const bf16x8* Ah = (const bf16x8*)A_hi;
    const bf16x8* Ef = (const bf16x8*)Efrag;

#pragma unroll
    for (int s = 0; s < 4; ++s) {
        const int kg = 4 * s + q;
        bf16x8 a[4], b[4];
#pragma unroll
        for (int fm = 0; fm < 4; ++fm)
            a[fm] = Ah[kg * 512 + b0 + wm * 64 + fm * 16 + c];
#pragma unroll
        for (int fn = 0; fn < 4; ++fn)
            b[fn] = Ef[(size_t)kg * NVP + v0 + wn * 64 + fn * 16 + c];
#pragma unroll
        for (int fm = 0; fm < 4; ++fm)
#pragma unroll
            for (int fn = 0; fn < 4; ++fn)
                acc[fm][fn] = __builtin_amdgcn_mfma_f32_16x16x32_bf16(
                    a[fm], b[fn], acc[fm][fn], 0, 0, 0);
    }

#pragma unroll
    for (int fm = 0; fm < 4; ++fm) {
        int row_base = b0 + wm * 64 + fm * 16 + q * 4;
#pragma unroll
        for (int fn = 0; fn < 4; ++fn) {
            int col = v0 + wn * 64 + fn * 16 + c;
            if (col < NV) {
#pragma unroll
                for (int r = 0; r < 4; ++r)
                    out[(size_t)(row_base + r) * NV + col] = acc[fm][fn][r];
            }
        }
    }
}

// ---------------------------------------------------------------------------
extern "C" void kernel_launch(void* const* d_in, const int* in_sizes, int n_in,
                              void* d_out, int out_size, void* d_ws, size_t ws_size,
                              hipStream_t stream)
{
    const int*   seq    = (const int*)  d_in[0];
    const int*   lens   = (const int*)  d_in[1];
    const int*   nei    = (const int*)  d_in[2];
    const float* wei    = (const float*)d_in[3];
    const float* s_vec  = (const float*)d_in[4];
    const float* E_tag  = (const float*)d_in[5];
    const float* E_ggnn = (const float*)d_in[6];
    const float* E_glob = (const float*)d_in[7];
    const float* W_ih   = (const float*)d_in[8];
    const float* b_ih   = (const float*)d_in[9];
    const float* W_hh   = (const float*)d_in[10];
    const float* b_hh   = (const float*)d_in[11];
    const float* Wout_w = (const float*)d_in[12];
    const float* Wout_b = (const float*)d_in[13];
    const float* W_w    = (const float*)d_in[14];
    const float* W3_w   = (const float*)d_in[15];
    const float* W3_b   = (const float*)d_in[16];
    const float* W1_w   = (const float*)d_in[17];
    const float* W1_b   = (const float*)d_in[18];
    const float* q1_w   = (const float*)d_in[19];
    const float* W2_w   = (const float*)d_in[20];
    const float* W2_b   = (const float*)d_in[21];
    const float* G1_w   = (const float*)d_in[22];
    const float* G1_b   = (const float*)d_in[23];
    const float* G2_w   = (const float*)d_in[24];
    const float* G2_b   = (const float*)d_in[25];

    float* out = (float*)d_out;
    // d_out staging (all consumed before out_gemm writes):
    //   G bf16   [0 .. 7.68M floats)
    //   Afrag    at float-offset 16M (48*25600*8 ushorts)
    //   Bfrag    at float-offset 21M (48*640*8 ushorts)
    unsigned short* Gm    = (unsigned short*)out;
    unsigned short* Afrag = (unsigned short*)(out + 16000000);
    unsigned short* Bfrag = (unsigned short*)(out + 21000000);

    // d_ws layout (floats):
    float* ws       = (float*)d_ws;
    float* h0       = ws;                           // 2.56M
    float* partialT = ws + 2560000;                 // 100*NEB = 156.4K
    float* ebar     = ws + 2720000;                 // 128
    unsigned short* A_hi  = (unsigned short*)(ws + 2724000);   // 65536 ushorts
    unsigned short* Efrag = (unsigned short*)(ws + 3000000);   // 16*NVP*8 ushorts

    prep_E<<<NEB, 256, 0, stream>>>(E_tag, Efrag, partialT);
    ebar_final<<<ND, 256, 0, stream>>>(partialT, ebar);
    prep_A<<<NBL / 32, 256, 0, stream>>>(seq, lens, E_ggnn, Afrag);
    prep_B<<<(48 * 640 + 255) / 256, 256, 0, stream>>>(W_ih, W_hh, Bfrag);
    gates_mfma<<<dim3(NBL / 128, 5), 256, 0, stream>>>(Afrag, Bfrag, Gm);
    gru2<<<(NBL * ND + 255) / 256, 256, 0, stream>>>(seq, E_ggnn, Gm, b_ih, b_hh, h0);
    fuse_kernel<<<NB, 128, 0, stream>>>(seq, lens, nei, wei, s_vec, E_tag, E_glob,
                                        Wout_w, Wout_b, W_w, W3_w, W3_b,
                                        W1_w, W1_b, q1_w, W2_w, W2_b,
                                        G1_w, G1_b, G2_w, G2_b, ebar, h0, A_hi);
    out_gemm_mfma<<<dim3(NVP / 128, NB / 128), 256, 0, stream>>>(A_hi, Efrag, out);
}

// Round 7
// 206.512 us; speedup vs baseline: 1.5599x; 1.0668x over previous
//
#include <hip/hip_runtime.h>
#include <math.h>

namespace {
constexpr int NB = 512;
constexpr int NL = 50;
constexpr int NKN = 32;
constexpr int ND = 100;
constexpr int NV = 100000;
constexpr int NBL = NB * NL;          // 25600
constexpr int NVP = 100096;           // 782*128, padded V for Efrag
constexpr int NEB = 1564;             // prep_E blocks (64 rows each)
constexpr int NAB = 800;              // prep_A blocks (32 rows each)
constexpr int NB2FRAG = 7 * 144 * 16; // 16128 fragment-rows in B2
constexpr int NB2BLK = (NB2FRAG + 255) / 256;  // 63
}

typedef __attribute__((ext_vector_type(8))) short bf16x8;
typedef __attribute__((ext_vector_type(8))) short short8v;
typedef __attribute__((ext_vector_type(4))) float f32x4;

__device__ inline unsigned short f2bf(float x) {
    unsigned u = __float_as_uint(x);
    unsigned r = (u + 0x7fffu + ((u >> 16) & 1u)) >> 16;
    return (unsigned short)r;
}
__device__ inline float bf2f(unsigned short h) {
    return __uint_as_float(((unsigned)h) << 16);
}

// ---------------------------------------------------------------------------
// mega_prep: blockIdx-partitioned prep phases (all independent):
//   [0, NEB)              prep_E : E_tag -> Efrag[kg 0..15][NVP][8] + partialT
//   [NEB, NEB+NAB)        prep_A : Afrag[kg 0..47][NBL][8]  (u | v | x segs)
//   [NEB+NAB, +NB2BLK)    prep_B2: gate-interleaved W fragments
//      B2 frag addr = ((chunk*144 + slot)*16 + c)*8,  d = chunk*16+c
//      slot<96 : g=slot>>5, kg=slot&31, seg=kg>>4, kap=(kg&15)*8+j
//                val = W_ih[(seg*100+kap)*300 + g*100 + d]
//      slot>=96: s2=slot-96, g=s2>>4, kgp=s2&15, kap=kgp*8+j
//                val = W_hh[kap*300 + g*100 + d]
// ---------------------------------------------------------------------------
__global__ __launch_bounds__(256) void mega_prep(
    const float* __restrict__ E_tag, unsigned short* __restrict__ Efrag,
    float* __restrict__ partialT,
    const int* __restrict__ seq, const int* __restrict__ lens,
    const float* __restrict__ E_ggnn, unsigned short* __restrict__ Afrag,
    const float* __restrict__ W_ih, const float* __restrict__ W_hh,
    unsigned short* __restrict__ B2)
{
    __shared__ __align__(16) char shbuf[25856];
    const int tid = threadIdx.x;
    const int blk = blockIdx.x;

    if (blk < NEB) {
        // ---------------- prep_E ----------------
        float (*es)[100] = (float(*)[100])shbuf;
        const int v0 = blk * 64;
        for (int idx = tid; idx < 1600; idx += 256) {
            size_t base = (size_t)v0 * 100 + (size_t)idx * 4;
            float4 e = make_float4(0.f, 0.f, 0.f, 0.f);
            if (base + 3 < (size_t)NV * ND) e = *(const float4*)(E_tag + base);
            int row = idx / 25, c4 = (idx - row * 25) * 4;
            es[row][c4]     = e.x;
            es[row][c4 + 1] = e.y;
            es[row][c4 + 2] = e.z;
            es[row][c4 + 3] = e.w;
        }
        __syncthreads();

        if (tid < ND) {
            float a = 0.f;
#pragma unroll 8
            for (int rr = 0; rr < 64; ++rr) a += es[rr][tid];
            partialT[(size_t)tid * NEB + blk] = a;
        }
        for (int idx = tid; idx < 16 * 64; idx += 256) {
            int kg = idx >> 6, vloc = idx & 63;
            short8v o;
#pragma unroll
            for (int j = 0; j < 8; ++j) {
                int k = kg * 8 + j;
                o[j] = (short)((k < ND) ? f2bf(es[vloc][k]) : 0);
            }
            *(short8v*)(Efrag + ((size_t)kg * NVP + v0 + vloc) * 8) = o;
        }
    } else if (blk < NEB + NAB) {
        // ---------------- prep_A ----------------
        float (*xs)[100] = (float(*)[100])shbuf;
        float* eo_s = (float*)(shbuf + 13600);
        float* ei_s = eo_s + 34;
        const int r0 = (blk - NEB) * 32;

        for (int idx = tid; idx < 34 * 25; idx += 256) {
            int row = idx / 25, qq = idx - row * 25;
            int rg = r0 - 1 + row;
            rg = rg < 0 ? 0 : (rg >= NBL ? NBL - 1 : rg);
            float4 e = *(const float4*)(E_ggnn + (size_t)seq[rg] * ND + 4 * qq);
            xs[row][4 * qq]     = e.x;
            xs[row][4 * qq + 1] = e.y;
            xs[row][4 * qq + 2] = e.z;
            xs[row][4 * qq + 3] = e.w;
        }
        for (int rr = tid; rr < 34; rr += 256) {
            int rg = r0 - 1 + rr;
            int rc = rg < 0 ? 0 : (rg >= NBL ? NBL - 1 : rg);
            int b = rc / NL, l = rc - b * NL;
            int lenb = lens[b];
            eo_s[rr] = (l < lenb - 1) ? 1.f : 0.f;
            ei_s[rr] = (l >= 1 && l <= lenb - 1) ? 1.f : 0.f;
        }
        __syncthreads();

        for (int idx = tid; idx < 32 * 48; idx += 256) {
            int rloc = idx / 48, kg = idx - rloc * 48;
            int seg = kg >> 4, kk = kg & 15;
            short8v o;
            float eo = eo_s[1 + rloc], ei = ei_s[1 + rloc];
#pragma unroll
            for (int j = 0; j < 8; ++j) {
                int k = kk * 8 + j;
                float v = 0.f;
                if (k < 100) {
                    if (seg == 0)      v = xs[1 + rloc][k] + eo * xs[2 + rloc][k];
                    else if (seg == 1) v = xs[1 + rloc][k] + ei * xs[rloc][k];
                    else               v = xs[1 + rloc][k];
                }
                o[j] = (short)f2bf(v);
            }
            *(short8v*)(Afrag + ((size_t)kg * NBL + r0 + rloc) * 8) = o;
        }
    } else {
        // ---------------- prep_B2 ----------------
        int idx = (blk - NEB - NAB) * 256 + tid;
        if (idx >= NB2FRAG) return;
        int chunk = idx / 2304;
        int rem = idx - chunk * 2304;
        int slot = rem >> 4, c = rem & 15;
        int d = chunk * 16 + c;
        short8v o;
        if (slot < 96) {
            int g = slot >> 5, kg = slot & 31;
            int seg = kg >> 4, kap0 = (kg & 15) * 8;
#pragma unroll
            for (int j = 0; j < 8; ++j) {
                int kap = kap0 + j;
                float v = (kap < 100 && d < 100)
                          ? W_ih[(seg * 100 + kap) * 300 + g * 100 + d] : 0.f;
                o[j] = (short)f2bf(v);
            }
        } else {
            int s2 = slot - 96;
            int g = s2 >> 4, kgp = s2 & 15;
            int kap0 = kgp * 8;
#pragma unroll
            for (int j = 0; j < 8; ++j) {
                int kap = kap0 + j;
                float v = (kap < 100 && d < 100)
                          ? W_hh[kap * 300 + g * 100 + d] : 0.f;
                o[j] = (short)f2bf(v);
            }
        }
        *(short8v*)(B2 + (size_t)idx * 8) = o;
    }
}

// ebar_final: one block per column d, coalesced strip reduce.
__global__ __launch_bounds__(256) void ebar_final(const float* __restrict__ partialT,
                                                  float* __restrict__ ebar)
{
    const int d = blockIdx.x;             // 0..99
    const int tid = threadIdx.x;
    float a = 0.f;
    for (int i = tid; i < NEB; i += 256) a += partialT[(size_t)d * NEB + i];
#pragma unroll
    for (int off = 32; off > 0; off >>= 1) a += __shfl_down(a, off);
    __shared__ float wsum[4];
    if ((tid & 63) == 0) wsum[tid >> 6] = a;
    __syncthreads();
    if (tid == 0)
        ebar[d] = (wsum[0] + wsum[1] + wsum[2] + wsum[3]) * (1.f / (float)NV);
}

// ---------------------------------------------------------------------------
// gates_gru: fused gates-GEMM (MFMA bf16) + GRU epilogue -> h0 directly.
//   Block: 256 thr = 4 waves; rows = blockIdx.x*128, wave w owns 32 rows.
//   blockIdx.y: 0 -> chunks 0..3, 1 -> chunks 4..6 (d-chunks of 16).
//   Per chunk: acc[fm 0..1][gate 0..5]; i-gates 8 K-steps (u,v segs),
//   h-gates 4 K-steps (x seg); then GRU in-register, write h0.
// ---------------------------------------------------------------------------
__global__ __launch_bounds__(256) void gates_gru(
    const int* __restrict__ seq,
    const unsigned short* __restrict__ Afrag,
    const unsigned short* __restrict__ B2,
    const float* __restrict__ b_ih, const float* __restrict__ b_hh,
    const float* __restrict__ E_ggnn,
    float* __restrict__ h0)
{
    const int tid = threadIdx.x;
    const int r0  = blockIdx.x * 128;
    const int cc0 = blockIdx.y ? 4 : 0;
    const int cc1 = blockIdx.y ? 7 : 4;
    const int lane = tid & 63;
    const int w = tid >> 6;
    const int q = lane >> 4, c = lane & 15;

    const bf16x8* Ap = (const bf16x8*)Afrag;
    const bf16x8* Bp = (const bf16x8*)B2;

    const int rowA = r0 + w * 32 + c;          // A-frag row (fm adds 16)

    // hoist tokens for epilogue rows: row = r0 + w*32 + fm*16 + q*4 + reg
    int tok[8];
#pragma unroll
    for (int fm = 0; fm < 2; ++fm)
#pragma unroll
        for (int reg = 0; reg < 4; ++reg)
            tok[fm * 4 + reg] = seq[r0 + w * 32 + fm * 16 + q * 4 + reg];

    for (int cc = cc0; cc < cc1; ++cc) {
        f32x4 acc[2][6];
#pragma unroll
        for (int fm = 0; fm < 2; ++fm)
#pragma unroll
            for (int g = 0; g < 6; ++g) acc[fm][g] = (f32x4)0.f;

        const size_t bbase = (size_t)cc * 144;

        // i-gates: 8 K-steps over segs u (kg 0..15) and v (kg 16..31)
#pragma unroll
        for (int st = 0; st < 8; ++st) {
            const int kg = 4 * st + q;
            bf16x8 a0 = Ap[(size_t)kg * NBL + rowA];
            bf16x8 a1 = Ap[(size_t)kg * NBL + rowA + 16];
            bf16x8 b0 = Bp[(bbase + 0 * 32 + kg) * 16 + c];
            bf16x8 b1 = Bp[(bbase + 1 * 32 + kg) * 16 + c];
            bf16x8 b2 = Bp[(bbase + 2 * 32 + kg) * 16 + c];
            acc[0][0] = __builtin_amdgcn_mfma_f32_16x16x32_bf16(a0, b0, acc[0][0], 0, 0, 0);
            acc[1][0] = __builtin_amdgcn_mfma_f32_16x16x32_bf16(a1, b0, acc[1][0], 0, 0, 0);
            acc[0][1] = __builtin_amdgcn_mfma_f32_16x16x32_bf16(a0, b1, acc[0][1], 0, 0, 0);
            acc[1][1] = __builtin_amdgcn_mfma_f32_16x16x32_bf16(a1, b1, acc[1][1], 0, 0, 0);
            acc[0][2] = __builtin_amdgcn_mfma_f32_16x16x32_bf16(a0, b2, acc[0][2], 0, 0, 0);
            acc[1][2] = __builtin_amdgcn_mfma_f32_16x16x32_bf16(a1, b2, acc[1][2], 0, 0, 0);
        }
        // h-gates: 4 K-steps over seg x (A kg 32..47, B kgp 0..15)
#pragma unroll
        for (int st = 0; st < 4; ++st) {
            const int kgp = 4 * st + q;
            const int kg  = 32 + kgp;
            bf16x8 a0 = Ap[(size_t)kg * NBL + rowA];
            bf16x8 a1 = Ap[(size_t)kg * NBL + rowA + 16];
            bf16x8 b0 = Bp[(bbase + 96 + 0 * 16 + kgp) * 16 + c];
            bf16x8 b1 = Bp[(bbase + 96 + 1 * 16 + kgp) * 16 + c];
            bf16x8 b2 = Bp[(bbase + 96 + 2 * 16 + kgp) * 16 + c];
            acc[0][3] = __builtin_amdgcn_mfma_f32_16x16x32_bf16(a0, b0, acc[0][3], 0, 0, 0);
            acc[1][3] = __builtin_amdgcn_mfma_f32_16x16x32_bf16(a1, b0, acc[1][3], 0, 0, 0);
            acc[0][4] = __builtin_amdgcn_mfma_f32_16x16x32_bf16(a0, b1, acc[0][4], 0, 0, 0);
            acc[1][4] = __builtin_amdgcn_mfma_f32_16x16x32_bf16(a1, b1, acc[1][4], 0, 0, 0);
            acc[0][5] = __builtin_amdgcn_mfma_f32_16x16x32_bf16(a0, b2, acc[0][5], 0, 0, 0);
            acc[1][5] = __builtin_amdgcn_mfma_f32_16x16x32_bf16(a1, b2, acc[1][5], 0, 0, 0);
        }

        // GRU epilogue: lane c holds d = cc*16+c for rows q*4+reg (+fm*16)
        const int d = cc * 16 + c;
        if (d < ND) {
            const float bi0 = b_ih[d], bi1 = b_ih[100 + d], bi2 = b_ih[200 + d];
            const float bh0 = b_hh[d], bh1 = b_hh[100 + d], bh2 = b_hh[200 + d];
#pragma unroll
            for (int fm = 0; fm < 2; ++fm) {
                const int rbase = r0 + w * 32 + fm * 16 + q * 4;
#pragma unroll
                for (int reg = 0; reg < 4; ++reg) {
                    const int row = rbase + reg;
                    float ir = acc[fm][0][reg] + bi0;
                    float iz = acc[fm][1][reg] + bi1;
                    float ig = acc[fm][2][reg] + bi2;
                    float hr = acc[fm][3][reg] + bh0;
                    float hz = acc[fm][4][reg] + bh1;
                    float hg = acc[fm][5][reg] + bh2;
                    float x  = E_ggnn[(size_t)tok[fm * 4 + reg] * ND + d];
                    float rg = 1.f / (1.f + expf(-(ir + hr)));
                    float zg = 1.f / (1.f + expf(-(iz + hz)));
                    float ng = tanhf(ig + rg * hg);
                    h0[(size_t)row * ND + d] = (1.f - zg) * ng + zg * x;
                }
            }
        }
    }
}

// ---------------------------------------------------------------------------
// K45: per-batch fused tail -> sess2 bf16 fragments A[kg 0..15][512][8]
// ---------------------------------------------------------------------------
__global__ __launch_bounds__(128) void fuse_kernel(
    const int* __restrict__ seq, const int* __restrict__ lens,
    const int* __restrict__ nei, const float* __restrict__ wei,
    const float* __restrict__ s_vec, const float* __restrict__ E_tag,
    const float* __restrict__ E_glob,
    const float* __restrict__ Wout_w, const float* __restrict__ Wout_b,
    const float* __restrict__ W_w,
    const float* __restrict__ W3_w, const float* __restrict__ W3_b,
    const float* __restrict__ W1_w, const float* __restrict__ W1_b,
    const float* __restrict__ q1_w,
    const float* __restrict__ W2_w, const float* __restrict__ W2_b,
    const float* __restrict__ G1_w, const float* __restrict__ G1_b,
    const float* __restrict__ G2_w, const float* __restrict__ G2_b,
    const float* __restrict__ ebar, const float* __restrict__ h0,
    unsigned short* __restrict__ A_hi)
{
    const int b = blockIdx.x, tid = threadIdx.x;
    __shared__ float t_emb[100], tw[100], twW[100], red[128];
    __shared__ float al[50], att[50];
    __shared__ float g0[100], cc[300], sess_s[100];
    __shared__ float sv[100], hnei[32][100], msg[100], xg[100], xg2[100];
    __shared__ float attg[32], score[32];
    __shared__ float scalars[4];      // 0: bd, 1: sm, 2: mean_b, 3: gate

    int lenb   = lens[b];
    int last_r = b * NL + (lenb - 1);
    int target = seq[last_r];

    if (tid < ND) {
        t_emb[tid] = E_tag[(size_t)target * ND + tid];
        sv[tid]    = s_vec[b * ND + tid];
    }
    __syncthreads();

    if (tid < ND) {
        float a = 0.f;
        for (int k = 0; k < ND; ++k) a += t_emb[k] * W_w[k * ND + tid];
        tw[tid] = a;
    }
    __syncthreads();

    if (tid < ND) {
        float a = 0.f;
        for (int d = 0; d < ND; ++d) a += Wout_w[tid * ND + d] * tw[d];
        twW[tid] = a;
    }
    red[tid] = (tid < ND) ? Wout_b[tid] * tw[tid] : 0.f;
    __syncthreads();
    for (int s = 64; s > 0; s >>= 1) { if (tid < s) red[tid] += red[tid + s]; __syncthreads(); }
    if (tid == 0) scalars[0] = red[0];
    __syncthreads();

    if (tid < NL) {
        const float* hr = h0 + (size_t)(b * NL + tid) * ND;
        float a = scalars[0];
        for (int k = 0; k < ND; ++k) a += hr[k] * twW[k];
        al[tid] = a;
    }
    __syncthreads();
    if (tid == 0) {
        float m = -1e30f;
        for (int l = 0; l < NL; ++l) m = fmaxf(m, al[l]);
        float s = 0.f;
        for (int l = 0; l < NL; ++l) { float e = expf(al[l] - m); att[l] = e; s += e; }
        float inv = 1.f / s, sm = 0.f;
        for (int l = 0; l < NL; ++l) { att[l] *= inv; if (l < lenb) sm += att[l]; }
        scalars[1] = sm;
    }
    __syncthreads();

    if (tid < ND) {
        float a = 0.f;
        for (int l = 0; l < lenb; ++l) a += att[l] * h0[(size_t)(b * NL + l) * ND + tid];
        g0[tid] = a;
    }
    __syncthreads();
    if (tid < ND) {
        float hg = 0.f, hl = 0.f;
        const float* hlast = h0 + (size_t)last_r * ND;
        for (int k = 0; k < ND; ++k) {
            float w = Wout_w[k * ND + tid];
            hg += g0[k] * w;
            hl += hlast[k] * w;
        }
        cc[tid]        = hg + scalars[1] * Wout_b[tid];
        cc[100 + tid]  = hl + Wout_b[tid];
        cc[200 + tid]  = t_emb[tid];
    }
    __syncthreads();

    if (tid < ND) {
        float a = W3_b[tid];
        for (int j = 0; j < 300; ++j) a += cc[j] * W3_w[j * ND + tid];
        sess_s[tid] = tanhf(a);
    }
    __syncthreads();
    red[tid] = (tid < ND) ? sess_s[tid] * ebar[tid] : 0.f;
    __syncthreads();
    for (int s = 64; s > 0; s >>= 1) { if (tid < s) red[tid] += red[tid + s]; __syncthreads(); }
    if (tid == 0) scalars[2] = red[0];
    __syncthreads();

    // ---- global encoder ----
    for (int idx = tid; idx < NKN * ND; idx += 128) {
        int k = idx / ND, d = idx - k * ND;
        hnei[k][d] = E_glob[(size_t)nei[b * NKN + k] * ND + d];
    }
    __syncthreads();

    {
        const int wv = tid >> 6, lane = tid & 63;
        for (int k2 = 0; k2 < NKN / 2; ++k2) {
            int k = k2 * 2 + wv;
            float p = 0.f;
            if (lane < 50) {
                float wk = wei[b * NKN + k];
                float a0 = W1_b[lane]      + wk * W1_w[100 * ND + lane];
                float a1 = W1_b[lane + 50] + wk * W1_w[100 * ND + lane + 50];
                for (int j = 0; j < ND; ++j) {
                    float t = hnei[k][j] * sv[j];
                    a0 += t * W1_w[j * ND + lane];
                    a1 += t * W1_w[j * ND + lane + 50];
                }
                p = tanhf(a0) * q1_w[lane] + tanhf(a1) * q1_w[lane + 50];
            }
            for (int off = 32; off > 0; off >>= 1) p += __shfl_down(p, off);
            if (lane == 0) score[k] = p;
        }
    }
    __syncthreads();

    if (tid == 0) {
        float m = -1e30f;
        for (int k = 0; k < NKN; ++k) m = fmaxf(m, score[k]);
        float s = 0.f;
        for (int k = 0; k < NKN; ++k) { float e = expf(score[k] - m); attg[k] = e; s += e; }
        float inv = 1.f / s;
        for (int k = 0; k < NKN; ++k) attg[k] *= inv;
    }
    __syncthreads();
    if (tid < ND) {
        float a = 0.f;
        for (int k = 0; k < NKN; ++k) a += attg[k] * hnei[k][tid];
        msg[tid] = a;
        xg[tid]  = E_glob[(size_t)target * ND + tid];
    }
    __syncthreads();
    if (tid < ND) {
        float a = W2_b[tid];
        for (int j = 0; j < ND; ++j) a += xg[j]  * W2_w[j * ND + tid];
        for (int j = 0; j < ND; ++j) a += msg[j] * W2_w[(100 + j) * ND + tid];
        xg2[tid] = fmaxf(a, 0.f);
    }
    __syncthreads();
    const float SCALE = (float)(1.0 - 49.0 / 50.0);
    if (tid < ND) {
        float a = W2_b[tid];
        for (int j = 0; j < ND; ++j) a += xg2[j] * W2_w[j * ND + tid];
        for (int j = 0; j < ND; ++j) a += msg[j] * W2_w[(100 + j) * ND + tid];
        xg[tid] = fmaxf(a, 0.f) * SCALE;
    }
    __syncthreads();

    if (tid < ND) {
        float a = G1_b[tid] + scalars[2] * G1_w[tid];
        for (int j = 0; j < ND; ++j) a += xg[j] * G1_w[(1 + j) * ND + tid];
        red[tid] = tanhf(a) * G2_w[tid];
    } else red[tid] = 0.f;
    __syncthreads();
    for (int s = 64; s > 0; s >>= 1) { if (tid < s) red[tid] += red[tid + s]; __syncthreads(); }
    if (tid == 0) scalars[3] = 1.f / (1.f + expf(-(red[0] + G2_b[0])));
    __syncthreads();

    {
        float val = 0.f;
        if (tid < ND) {
            float g = scalars[3];
            val = g * xg[tid] + (1.f - g) * scalars[2];
        }
        int kgrp = tid >> 3, j = tid & 7;
        A_hi[kgrp * 4096 + b * 8 + j] = f2bf(val);
    }
}

// ---------------------------------------------------------------------------
// K6: out = sess2 @ E_tag^T, streaming MFMA: no LDS, frags from global.
// ---------------------------------------------------------------------------
__global__ __launch_bounds__(256) void out_gemm_mfma(
    const unsigned short* __restrict__ A_hi,
    const unsigned short* __restrict__ Efrag,
    float* __restrict__ out)
{
    const int tid = threadIdx.x;
    const int v0  = blockIdx.x * 128;
    const int b0  = blockIdx.y * 128;
    const int lane = tid & 63;
    const int wv = tid >> 6;
    const int wm = wv >> 1, wn = wv & 1;
    const int q = lane >> 4, c = lane & 15;

    f32x4 acc[4][4];
#pragma unroll
    for (int fm = 0; fm < 4; ++fm)
#pragma unroll
        for (int fn = 0; fn < 4; ++fn) acc[fm][fn] = (f32x4)0.f;

    const bf16x8* Ah = (const bf16x8*)A_hi;
    const bf16x8* Ef = (const bf16x8*)Efrag;

#pragma unroll
    for (int s = 0; s < 4; ++s) {
        const int kg = 4 * s + q;
        bf16x8 a[4], b[4];
#pragma unroll
        for (int fm = 0; fm < 4; ++fm)
            a[fm] = Ah[kg * 512 + b0 + wm * 64 + fm * 16 + c];
#pragma unroll
        for (int fn = 0; fn < 4; ++fn)
            b[fn] = Ef[(size_t)kg * NVP + v0 + wn * 64 + fn * 16 + c];
#pragma unroll
        for (int fm = 0; fm < 4; ++fm)
#pragma unroll
            for (int fn = 0; fn < 4; ++fn)
                acc[fm][fn] = __builtin_amdgcn_mfma_f32_16x16x32_bf16(
                    a[fm], b[fn], acc[fm][fn], 0, 0, 0);
    }

#pragma unroll
    for (int fm = 0; fm < 4; ++fm) {
        int row_base = b0 + wm * 64 + fm * 16 + q * 4;
#pragma unroll
        for (int fn = 0; fn < 4; ++fn) {
            int col = v0 + wn * 64 + fn * 16 + c;
            if (col < NV) {
#pragma unroll
                for (int r = 0; r < 4; ++r)
                    out[(size_t)(row_base + r) * NV + col] = acc[fm][fn][r];
            }
        }
    }
}

// ---------------------------------------------------------------------------
extern "C" void kernel_launch(void* const* d_in, const int* in_sizes, int n_in,
                              void* d_out, int out_size, void* d_ws, size_t ws_size,
                              hipStream_t stream)
{
    const int*   seq    = (const int*)  d_in[0];
    const int*   lens   = (const int*)  d_in[1];
    const int*   nei    = (const int*)  d_in[2];
    const float* wei    = (const float*)d_in[3];
    const float* s_vec  = (const float*)d_in[4];
    const float* E_tag  = (const float*)d_in[5];
    const float* E_ggnn = (const float*)d_in[6];
    const float* E_glob = (const float*)d_in[7];
    const float* W_ih   = (const float*)d_in[8];
    const float* b_ih   = (const float*)d_in[9];
    const float* W_hh   = (const float*)d_in[10];
    const float* b_hh   = (const float*)d_in[11];
    const float* Wout_w = (const float*)d_in[12];
    const float* Wout_b = (const float*)d_in[13];
    const float* W_w    = (const float*)d_in[14];
    const float* W3_w   = (const float*)d_in[15];
    const float* W3_b   = (const float*)d_in[16];
    const float* W1_w   = (const float*)d_in[17];
    const float* W1_b   = (const float*)d_in[18];
    const float* q1_w   = (const float*)d_in[19];
    const float* W2_w   = (const float*)d_in[20];
    const float* W2_b   = (const float*)d_in[21];
    const float* G1_w   = (const float*)d_in[22];
    const float* G1_b   = (const float*)d_in[23];
    const float* G2_w   = (const float*)d_in[24];
    const float* G2_b   = (const float*)d_in[25];

    float* out = (float*)d_out;
    // d_out staging (consumed by gates_gru before out_gemm overwrites):
    //   Afrag at float-offset 16M (48*25600*8 ushorts = 4.92M floats)
    //   B2    at float-offset 21M (16128*8 ushorts)
    unsigned short* Afrag = (unsigned short*)(out + 16000000);
    unsigned short* B2    = (unsigned short*)(out + 21000000);

    // d_ws layout (floats):
    float* ws       = (float*)d_ws;
    float* h0       = ws;                           // 2.56M
    float* partialT = ws + 2560000;                 // 100*NEB = 156.4K
    float* ebar     = ws + 2720000;                 // 128
    unsigned short* A_hi  = (unsigned short*)(ws + 2724000);   // 65536 ushorts
    unsigned short* Efrag = (unsigned short*)(ws + 3000000);   // 16*NVP*8 ushorts

    mega_prep<<<NEB + NAB + NB2BLK, 256, 0, stream>>>(
        E_tag, Efrag, partialT, seq, lens, E_ggnn, Afrag, W_ih, W_hh, B2);
    ebar_final<<<ND, 256, 0, stream>>>(partialT, ebar);
    gates_gru<<<dim3(NBL / 128, 2), 256, 0, stream>>>(seq, Afrag, B2, b_ih, b_hh,
                                                      E_ggnn, h0);
    fuse_kernel<<<NB, 128, 0, stream>>>(seq, lens, nei, wei, s_vec, E_tag, E_glob,
                                        Wout_w, Wout_b, W_w, W3_w, W3_b,
                                        W1_w, W1_b, q1_w, W2_w, W2_b,
                                        G1_w, G1_b, G2_w, G2_b, ebar, h0, A_hi);
    out_gemm_mfma<<<dim3(NVP / 128, NB / 128), 256, 0, stream>>>(A_hi, Efrag, out);
}

// Round 8
// 201.035 us; speedup vs baseline: 1.6024x; 1.0272x over previous
//
#include <hip/hip_runtime.h>
#include <math.h>

namespace {
constexpr int NB = 512;
constexpr int NL = 50;
constexpr int NKN = 32;
constexpr int ND = 100;
constexpr int NV = 100000;
constexpr int NBL = NB * NL;          // 25600
constexpr int NVP = 100096;           // 782*128, padded V for Efrag
constexpr int NEB = 1564;             // prep_E blocks (64 rows each)
constexpr int NAB = 800;              // prep_A blocks (32 rows each)
constexpr int NB2FRAG = 7 * 144 * 16; // 16128 fragment-rows in B2
constexpr int NB2BLK = (NB2FRAG + 255) / 256;  // 63
}

typedef __attribute__((ext_vector_type(8))) short bf16x8;
typedef __attribute__((ext_vector_type(8))) short short8v;
typedef __attribute__((ext_vector_type(4))) float f32x4;

__device__ inline unsigned short f2bf(float x) {
    unsigned u = __float_as_uint(x);
    unsigned r = (u + 0x7fffu + ((u >> 16) & 1u)) >> 16;
    return (unsigned short)r;
}
__device__ inline float bf2f(unsigned short h) {
    return __uint_as_float(((unsigned)h) << 16);
}

// ---------------------------------------------------------------------------
// mega_prep: blockIdx-partitioned prep phases (all independent):
//   [0, NEB)              prep_E : E_tag -> Efrag[kg 0..15][NVP][8] + partial
//   [NEB, NEB+NAB)        prep_A : Afrag[kg 0..47][NBL][8]  (u | v | x segs)
//   [NEB+NAB, +NB2BLK)    prep_B2: gate-interleaved W fragments
// ---------------------------------------------------------------------------
__global__ __launch_bounds__(256) void mega_prep(
    const float* __restrict__ E_tag, unsigned short* __restrict__ Efrag,
    float* __restrict__ partial,          // [NEB][100] coalesced per block
    const int* __restrict__ seq, const int* __restrict__ lens,
    const float* __restrict__ E_ggnn, unsigned short* __restrict__ Afrag,
    const float* __restrict__ W_ih, const float* __restrict__ W_hh,
    unsigned short* __restrict__ B2)
{
    __shared__ __align__(16) char shbuf[25856];
    const int tid = threadIdx.x;
    const int blk = blockIdx.x;

    if (blk < NEB) {
        // ---------------- prep_E ----------------
        float (*es)[100] = (float(*)[100])shbuf;
        const int v0 = blk * 64;
        for (int idx = tid; idx < 1600; idx += 256) {
            size_t base = (size_t)v0 * 100 + (size_t)idx * 4;
            float4 e = make_float4(0.f, 0.f, 0.f, 0.f);
            if (base + 3 < (size_t)NV * ND) e = *(const float4*)(E_tag + base);
            int row = idx / 25, c4 = (idx - row * 25) * 4;
            es[row][c4]     = e.x;
            es[row][c4 + 1] = e.y;
            es[row][c4 + 2] = e.z;
            es[row][c4 + 3] = e.w;
        }
        __syncthreads();

        if (tid < ND) {
            float a = 0.f;
#pragma unroll 8
            for (int rr = 0; rr < 64; ++rr) a += es[rr][tid];
            partial[(size_t)blk * ND + tid] = a;     // coalesced 400B
        }
        for (int idx = tid; idx < 16 * 64; idx += 256) {
            int kg = idx >> 6, vloc = idx & 63;
            short8v o;
#pragma unroll
            for (int j = 0; j < 8; ++j) {
                int k = kg * 8 + j;
                o[j] = (short)((k < ND) ? f2bf(es[vloc][k]) : 0);
            }
            *(short8v*)(Efrag + ((size_t)kg * NVP + v0 + vloc) * 8) = o;
        }
    } else if (blk < NEB + NAB) {
        // ---------------- prep_A ----------------
        float (*xs)[100] = (float(*)[100])shbuf;
        float* eo_s = (float*)(shbuf + 13600);
        float* ei_s = eo_s + 34;
        const int r0 = (blk - NEB) * 32;

        for (int idx = tid; idx < 34 * 25; idx += 256) {
            int row = idx / 25, qq = idx - row * 25;
            int rg = r0 - 1 + row;
            rg = rg < 0 ? 0 : (rg >= NBL ? NBL - 1 : rg);
            float4 e = *(const float4*)(E_ggnn + (size_t)seq[rg] * ND + 4 * qq);
            xs[row][4 * qq]     = e.x;
            xs[row][4 * qq + 1] = e.y;
            xs[row][4 * qq + 2] = e.z;
            xs[row][4 * qq + 3] = e.w;
        }
        for (int rr = tid; rr < 34; rr += 256) {
            int rg = r0 - 1 + rr;
            int rc = rg < 0 ? 0 : (rg >= NBL ? NBL - 1 : rg);
            int b = rc / NL, l = rc - b * NL;
            int lenb = lens[b];
            eo_s[rr] = (l < lenb - 1) ? 1.f : 0.f;
            ei_s[rr] = (l >= 1 && l <= lenb - 1) ? 1.f : 0.f;
        }
        __syncthreads();

        for (int idx = tid; idx < 32 * 48; idx += 256) {
            int rloc = idx / 48, kg = idx - rloc * 48;
            int seg = kg >> 4, kk = kg & 15;
            short8v o;
            float eo = eo_s[1 + rloc], ei = ei_s[1 + rloc];
#pragma unroll
            for (int j = 0; j < 8; ++j) {
                int k = kk * 8 + j;
                float v = 0.f;
                if (k < 100) {
                    if (seg == 0)      v = xs[1 + rloc][k] + eo * xs[2 + rloc][k];
                    else if (seg == 1) v = xs[1 + rloc][k] + ei * xs[rloc][k];
                    else               v = xs[1 + rloc][k];
                }
                o[j] = (short)f2bf(v);
            }
            *(short8v*)(Afrag + ((size_t)kg * NBL + r0 + rloc) * 8) = o;
        }
    } else {
        // ---------------- prep_B2 ----------------
        int idx = (blk - NEB - NAB) * 256 + tid;
        if (idx >= NB2FRAG) return;
        int chunk = idx / 2304;
        int rem = idx - chunk * 2304;
        int slot = rem >> 4, c = rem & 15;
        int d = chunk * 16 + c;
        short8v o;
        if (slot < 96) {
            int g = slot >> 5, kg = slot & 31;
            int seg = kg >> 4, kap0 = (kg & 15) * 8;
#pragma unroll
            for (int j = 0; j < 8; ++j) {
                int kap = kap0 + j;
                float v = (kap < 100 && d < 100)
                          ? W_ih[(seg * 100 + kap) * 300 + g * 100 + d] : 0.f;
                o[j] = (short)f2bf(v);
            }
        } else {
            int s2 = slot - 96;
            int g = s2 >> 4, kgp = s2 & 15;
            int kap0 = kgp * 8;
#pragma unroll
            for (int j = 0; j < 8; ++j) {
                int kap = kap0 + j;
                float v = (kap < 100 && d < 100)
                          ? W_hh[kap * 300 + g * 100 + d] : 0.f;
                o[j] = (short)f2bf(v);
            }
        }
        *(short8v*)(B2 + (size_t)idx * 8) = o;
    }
}

// ---------------------------------------------------------------------------
// gates_gru: fused gates-GEMM (MFMA bf16) + GRU epilogue -> h0 directly.
//   blockIdx.y: 0 -> chunks 0..3, 1 -> chunks 4..6 (d-chunks of 16),
//               2 -> ebar reduction (first 100 x-blocks; co-scheduled).
// ---------------------------------------------------------------------------
__global__ __launch_bounds__(256) void gates_gru(
    const int* __restrict__ seq,
    const unsigned short* __restrict__ Afrag,
    const unsigned short* __restrict__ B2,
    const float* __restrict__ b_ih, const float* __restrict__ b_hh,
    const float* __restrict__ E_ggnn,
    const float* __restrict__ partial, float* __restrict__ ebar,
    float* __restrict__ h0)
{
    __shared__ float wsum[4];
    const int tid = threadIdx.x;

    if (blockIdx.y == 2) {
        // ---- ebar reduction: block d sums partial[:, d] ----
        const int d = blockIdx.x;
        if (d >= ND) return;
        float a = 0.f;
        for (int i = tid; i < NEB; i += 256) a += partial[(size_t)i * ND + d];
#pragma unroll
        for (int off = 32; off > 0; off >>= 1) a += __shfl_down(a, off);
        if ((tid & 63) == 0) wsum[tid >> 6] = a;
        __syncthreads();
        if (tid == 0)
            ebar[d] = (wsum[0] + wsum[1] + wsum[2] + wsum[3]) * (1.f / (float)NV);
        return;
    }

    const int r0  = blockIdx.x * 128;
    const int cc0 = blockIdx.y ? 4 : 0;
    const int cc1 = blockIdx.y ? 7 : 4;
    const int lane = tid & 63;
    const int w = tid >> 6;
    const int q = lane >> 4, c = lane & 15;

    const bf16x8* Ap = (const bf16x8*)Afrag;
    const bf16x8* Bp = (const bf16x8*)B2;

    const int rowA = r0 + w * 32 + c;          // A-frag row (fm adds 16)

    int tok[8];
#pragma unroll
    for (int fm = 0; fm < 2; ++fm)
#pragma unroll
        for (int reg = 0; reg < 4; ++reg)
            tok[fm * 4 + reg] = seq[r0 + w * 32 + fm * 16 + q * 4 + reg];

    for (int cc = cc0; cc < cc1; ++cc) {
        f32x4 acc[2][6];
#pragma unroll
        for (int fm = 0; fm < 2; ++fm)
#pragma unroll
            for (int g = 0; g < 6; ++g) acc[fm][g] = (f32x4)0.f;

        const size_t bbase = (size_t)cc * 144;

        // i-gates: 8 K-steps over segs u (kg 0..15) and v (kg 16..31)
#pragma unroll
        for (int st = 0; st < 8; ++st) {
            const int kg = 4 * st + q;
            bf16x8 a0 = Ap[(size_t)kg * NBL + rowA];
            bf16x8 a1 = Ap[(size_t)kg * NBL + rowA + 16];
            bf16x8 b0 = Bp[(bbase + 0 * 32 + kg) * 16 + c];
            bf16x8 b1 = Bp[(bbase + 1 * 32 + kg) * 16 + c];
            bf16x8 b2 = Bp[(bbase + 2 * 32 + kg) * 16 + c];
            acc[0][0] = __builtin_amdgcn_mfma_f32_16x16x32_bf16(a0, b0, acc[0][0], 0, 0, 0);
            acc[1][0] = __builtin_amdgcn_mfma_f32_16x16x32_bf16(a1, b0, acc[1][0], 0, 0, 0);
            acc[0][1] = __builtin_amdgcn_mfma_f32_16x16x32_bf16(a0, b1, acc[0][1], 0, 0, 0);
            acc[1][1] = __builtin_amdgcn_mfma_f32_16x16x32_bf16(a1, b1, acc[1][1], 0, 0, 0);
            acc[0][2] = __builtin_amdgcn_mfma_f32_16x16x32_bf16(a0, b2, acc[0][2], 0, 0, 0);
            acc[1][2] = __builtin_amdgcn_mfma_f32_16x16x32_bf16(a1, b2, acc[1][2], 0, 0, 0);
        }
        // h-gates: 4 K-steps over seg x (A kg 32..47, B kgp 0..15)
#pragma unroll
        for (int st = 0; st < 4; ++st) {
            const int kgp = 4 * st + q;
            const int kg  = 32 + kgp;
            bf16x8 a0 = Ap[(size_t)kg * NBL + rowA];
            bf16x8 a1 = Ap[(size_t)kg * NBL + rowA + 16];
            bf16x8 b0 = Bp[(bbase + 96 + 0 * 16 + kgp) * 16 + c];
            bf16x8 b1 = Bp[(bbase + 96 + 1 * 16 + kgp) * 16 + c];
            bf16x8 b2 = Bp[(bbase + 96 + 2 * 16 + kgp) * 16 + c];
            acc[0][3] = __builtin_amdgcn_mfma_f32_16x16x32_bf16(a0, b0, acc[0][3], 0, 0, 0);
            acc[1][3] = __builtin_amdgcn_mfma_f32_16x16x32_bf16(a1, b0, acc[1][3], 0, 0, 0);
            acc[0][4] = __builtin_amdgcn_mfma_f32_16x16x32_bf16(a0, b1, acc[0][4], 0, 0, 0);
            acc[1][4] = __builtin_amdgcn_mfma_f32_16x16x32_bf16(a1, b1, acc[1][4], 0, 0, 0);
            acc[0][5] = __builtin_amdgcn_mfma_f32_16x16x32_bf16(a0, b2, acc[0][5], 0, 0, 0);
            acc[1][5] = __builtin_amdgcn_mfma_f32_16x16x32_bf16(a1, b2, acc[1][5], 0, 0, 0);
        }

        const int d = cc * 16 + c;
        if (d < ND) {
            const float bi0 = b_ih[d], bi1 = b_ih[100 + d], bi2 = b_ih[200 + d];
            const float bh0 = b_hh[d], bh1 = b_hh[100 + d], bh2 = b_hh[200 + d];
#pragma unroll
            for (int fm = 0; fm < 2; ++fm) {
                const int rbase = r0 + w * 32 + fm * 16 + q * 4;
#pragma unroll
                for (int reg = 0; reg < 4; ++reg) {
                    const int row = rbase + reg;
                    float ir = acc[fm][0][reg] + bi0;
                    float iz = acc[fm][1][reg] + bi1;
                    float ig = acc[fm][2][reg] + bi2;
                    float hr = acc[fm][3][reg] + bh0;
                    float hz = acc[fm][4][reg] + bh1;
                    float hg = acc[fm][5][reg] + bh2;
                    float x  = E_ggnn[(size_t)tok[fm * 4 + reg] * ND + d];
                    float rg = 1.f / (1.f + expf(-(ir + hr)));
                    float zg = 1.f / (1.f + expf(-(iz + hz)));
                    float ng = tanhf(ig + rg * hg);
                    h0[(size_t)row * ND + d] = (1.f - zg) * ng + zg * x;
                }
            }
        }
    }
}

// ---------------------------------------------------------------------------
// K45: per-batch fused tail -> sess2 bf16 fragments A[kg 0..15][512][8]
// ---------------------------------------------------------------------------
__global__ __launch_bounds__(128) void fuse_kernel(
    const int* __restrict__ seq, const int* __restrict__ lens,
    const int* __restrict__ nei, const float* __restrict__ wei,
    const float* __restrict__ s_vec, const float* __restrict__ E_tag,
    const float* __restrict__ E_glob,
    const float* __restrict__ Wout_w, const float* __restrict__ Wout_b,
    const float* __restrict__ W_w,
    const float* __restrict__ W3_w, const float* __restrict__ W3_b,
    const float* __restrict__ W1_w, const float* __restrict__ W1_b,
    const float* __restrict__ q1_w,
    const float* __restrict__ W2_w, const float* __restrict__ W2_b,
    const float* __restrict__ G1_w, const float* __restrict__ G1_b,
    const float* __restrict__ G2_w, const float* __restrict__ G2_b,
    const float* __restrict__ ebar, const float* __restrict__ h0,
    unsigned short* __restrict__ A_hi)
{
    const int b = blockIdx.x, tid = threadIdx.x;
    __shared__ float t_emb[100], tw[100], twW[100], red[128];
    __shared__ float al[50], att[50];
    __shared__ float g0[100], cc[300], sess_s[100];
    __shared__ float sv[100], hnei[32][100], msg[100], xg[100], xg2[100];
    __shared__ float attg[32], score[32];
    __shared__ float scalars[4];      // 0: bd, 1: sm, 2: mean_b, 3: gate

    int lenb   = lens[b];
    int last_r = b * NL + (lenb - 1);
    int target = seq[last_r];

    if (tid < ND) {
        t_emb[tid] = E_tag[(size_t)target * ND + tid];
        sv[tid]    = s_vec[b * ND + tid];
    }
    __syncthreads();

    if (tid < ND) {
        float a = 0.f;
        for (int k = 0; k < ND; ++k) a += t_emb[k] * W_w[k * ND + tid];
        tw[tid] = a;
    }
    __syncthreads();

    if (tid < ND) {
        float a = 0.f;
        for (int d = 0; d < ND; ++d) a += Wout_w[tid * ND + d] * tw[d];
        twW[tid] = a;
    }
    red[tid] = (tid < ND) ? Wout_b[tid] * tw[tid] : 0.f;
    __syncthreads();
    for (int s = 64; s > 0; s >>= 1) { if (tid < s) red[tid] += red[tid + s]; __syncthreads(); }
    if (tid == 0) scalars[0] = red[0];
    __syncthreads();

    if (tid < NL) {
        const float* hr = h0 + (size_t)(b * NL + tid) * ND;
        float a = scalars[0];
        for (int k = 0; k < ND; ++k) a += hr[k] * twW[k];
        al[tid] = a;
    }
    __syncthreads();
    if (tid == 0) {
        float m = -1e30f;
        for (int l = 0; l < NL; ++l) m = fmaxf(m, al[l]);
        float s = 0.f;
        for (int l = 0; l < NL; ++l) { float e = expf(al[l] - m); att[l] = e; s += e; }
        float inv = 1.f / s, sm = 0.f;
        for (int l = 0; l < NL; ++l) { att[l] *= inv; if (l < lenb) sm += att[l]; }
        scalars[1] = sm;
    }
    __syncthreads();

    if (tid < ND) {
        float a = 0.f;
        for (int l = 0; l < lenb; ++l) a += att[l] * h0[(size_t)(b * NL + l) * ND + tid];
        g0[tid] = a;
    }
    __syncthreads();
    if (tid < ND) {
        float hg = 0.f, hl = 0.f;
        const float* hlast = h0 + (size_t)last_r * ND;
        for (int k = 0; k < ND; ++k) {
            float w = Wout_w[k * ND + tid];
            hg += g0[k] * w;
            hl += hlast[k] * w;
        }
        cc[tid]        = hg + scalars[1] * Wout_b[tid];
        cc[100 + tid]  = hl + Wout_b[tid];
        cc[200 + tid]  = t_emb[tid];
    }
    __syncthreads();

    if (tid < ND) {
        float a = W3_b[tid];
        for (int j = 0; j < 300; ++j) a += cc[j] * W3_w[j * ND + tid];
        sess_s[tid] = tanhf(a);
    }
    __syncthreads();
    red[tid] = (tid < ND) ? sess_s[tid] * ebar[tid] : 0.f;
    __syncthreads();
    for (int s = 64; s > 0; s >>= 1) { if (tid < s) red[tid] += red[tid + s]; __syncthreads(); }
    if (tid == 0) scalars[2] = red[0];
    __syncthreads();

    // ---- global encoder ----
    for (int idx = tid; idx < NKN * ND; idx += 128) {
        int k = idx / ND, d = idx - k * ND;
        hnei[k][d] = E_glob[(size_t)nei[b * NKN + k] * ND + d];
    }
    __syncthreads();

    {
        const int wv = tid >> 6, lane = tid & 63;
        for (int k2 = 0; k2 < NKN / 2; ++k2) {
            int k = k2 * 2 + wv;
            float p = 0.f;
            if (lane < 50) {
                float wk = wei[b * NKN + k];
                float a0 = W1_b[lane]      + wk * W1_w[100 * ND + lane];
                float a1 = W1_b[lane + 50] + wk * W1_w[100 * ND + lane + 50];
                for (int j = 0; j < ND; ++j) {
                    float t = hnei[k][j] * sv[j];
                    a0 += t * W1_w[j * ND + lane];
                    a1 += t * W1_w[j * ND + lane + 50];
                }
                p = tanhf(a0) * q1_w[lane] + tanhf(a1) * q1_w[lane + 50];
            }
            for (int off = 32; off > 0; off >>= 1) p += __shfl_down(p, off);
            if (lane == 0) score[k] = p;
        }
    }
    __syncthreads();

    if (tid == 0) {
        float m = -1e30f;
        for (int k = 0; k < NKN; ++k) m = fmaxf(m, score[k]);
        float s = 0.f;
        for (int k = 0; k < NKN; ++k) { float e = expf(score[k] - m); attg[k] = e; s += e; }
        float inv = 1.f / s;
        for (int k = 0; k < NKN; ++k) attg[k] *= inv;
    }
    __syncthreads();
    if (tid < ND) {
        float a = 0.f;
        for (int k = 0; k < NKN; ++k) a += attg[k] * hnei[k][tid];
        msg[tid] = a;
        xg[tid]  = E_glob[(size_t)target * ND + tid];
    }
    __syncthreads();
    if (tid < ND) {
        float a = W2_b[tid];
        for (int j = 0; j < ND; ++j) a += xg[j]  * W2_w[j * ND + tid];
        for (int j = 0; j < ND; ++j) a += msg[j] * W2_w[(100 + j) * ND + tid];
        xg2[tid] = fmaxf(a, 0.f);
    }
    __syncthreads();
    const float SCALE = (float)(1.0 - 49.0 / 50.0);
    if (tid < ND) {
        float a = W2_b[tid];
        for (int j = 0; j < ND; ++j) a += xg2[j] * W2_w[j * ND + tid];
        for (int j = 0; j < ND; ++j) a += msg[j] * W2_w[(100 + j) * ND + tid];
        xg[tid] = fmaxf(a, 0.f) * SCALE;
    }
    __syncthreads();

    if (tid < ND) {
        float a = G1_b[tid] + scalars[2] * G1_w[tid];
        for (int j = 0; j < ND; ++j) a += xg[j] * G1_w[(1 + j) * ND + tid];
        red[tid] = tanhf(a) * G2_w[tid];
    } else red[tid] = 0.f;
    __syncthreads();
    for (int s = 64; s > 0; s >>= 1) { if (tid < s) red[tid] += red[tid + s]; __syncthreads(); }
    if (tid == 0) scalars[3] = 1.f / (1.f + expf(-(red[0] + G2_b[0])));
    __syncthreads();

    {
        float val = 0.f;
        if (tid < ND) {
            float g = scalars[3];
            val = g * xg[tid] + (1.f - g) * scalars[2];
        }
        int kgrp = tid >> 3, j = tid & 7;
        A_hi[kgrp * 4096 + b * 8 + j] = f2bf(val);
    }
}

// ---------------------------------------------------------------------------
// K6: out = sess2 @ E_tag^T, streaming MFMA: no LDS, frags from global.
// ---------------------------------------------------------------------------
__global__ __launch_bounds__(256) void out_gemm_mfma(
    const unsigned short* __restrict__ A_hi,
    const unsigned short* __restrict__ Efrag,
    float* __restrict__ out)
{
    const int tid = threadIdx.x;
    const int v0  = blockIdx.x * 128;
    const int b0  = blockIdx.y * 128;
    const int lane = tid & 63;
    const int wv = tid >> 6;
    const int wm = wv >> 1, wn = wv & 1;
    const int q = lane >> 4, c = lane & 15;

    f32x4 acc[4][4];
#pragma unroll
    for (int fm = 0; fm < 4; ++fm)
#pragma unroll
        for (int fn = 0; fn < 4; ++fn) acc[fm][fn] = (f32x4)0.f;

    const bf16x8* Ah = (const bf16x8*)A_hi;
    const bf16x8* Ef = (const bf16x8*)Efrag;

#pragma unroll
    for (int s = 0; s < 4; ++s) {
        const int kg = 4 * s + q;
        bf16x8 a[4], b[4];
#pragma unroll
        for (int fm = 0; fm < 4; ++fm)
            a[fm] = Ah[kg * 512 + b0 + wm * 64 + fm * 16 + c];
#pragma unroll
        for (int fn = 0; fn < 4; ++fn)
            b[fn] = Ef[(size_t)kg * NVP + v0 + wn * 64 + fn * 16 + c];
#pragma unroll
        for (int fm = 0; fm < 4; ++fm)
#pragma unroll
            for (int fn = 0; fn < 4; ++fn)
                acc[fm][fn] = __builtin_amdgcn_mfma_f32_16x16x32_bf16(
                    a[fm], b[fn], acc[fm][fn], 0, 0, 0);
    }

#pragma unroll
    for (int fm = 0; fm < 4; ++fm) {
        int row_base = b0 + wm * 64 + fm * 16 + q * 4;
#pragma unroll
        for (int fn = 0; fn < 4; ++fn) {
            int col = v0 + wn * 64 + fn * 16 + c;
            if (col < NV) {
#pragma unroll
                for (int r = 0; r < 4; ++r)
                    out[(size_t)(row_base + r) * NV + col] = acc[fm][fn][r];
            }
        }
    }
}

// ---------------------------------------------------------------------------
extern "C" void kernel_launch(void* const* d_in, const int* in_sizes, int n_in,
                              void* d_out, int out_size, void* d_ws, size_t ws_size,
                              hipStream_t stream)
{
    const int*   seq    = (const int*)  d_in[0];
    const int*   lens   = (const int*)  d_in[1];
    const int*   nei    = (const int*)  d_in[2];
    const float* wei    = (const float*)d_in[3];
    const float* s_vec  = (const float*)d_in[4];
    const float* E_tag  = (const float*)d_in[5];
    const float* E_ggnn = (const float*)d_in[6];
    const float* E_glob = (const float*)d_in[7];
    const float* W_ih   = (const float*)d_in[8];
    const float* b_ih   = (const float*)d_in[9];
    const float* W_hh   = (const float*)d_in[10];
    const float* b_hh   = (const float*)d_in[11];
    const float* Wout_w = (const float*)d_in[12];
    const float* Wout_b = (const float*)d_in[13];
    const float* W_w    = (const float*)d_in[14];
    const float* W3_w   = (const float*)d_in[15];
    const float* W3_b   = (const float*)d_in[16];
    const float* W1_w   = (const float*)d_in[17];
    const float* W1_b   = (const float*)d_in[18];
    const float* q1_w   = (const float*)d_in[19];
    const float* W2_w   = (const float*)d_in[20];
    const float* W2_b   = (const float*)d_in[21];
    const float* G1_w   = (const float*)d_in[22];
    const float* G1_b   = (const float*)d_in[23];
    const float* G2_w   = (const float*)d_in[24];
    const float* G2_b   = (const float*)d_in[25];

    float* out = (float*)d_out;
    // d_out staging (consumed by gates_gru before out_gemm overwrites):
    //   Afrag at float-offset 16M (48*25600*8 ushorts)
    //   B2    at float-offset 21M (16128*8 ushorts)
    unsigned short* Afrag = (unsigned short*)(out + 16000000);
    unsigned short* B2    = (unsigned short*)(out + 21000000);

    // d_ws layout (floats):
    float* ws      = (float*)d_ws;
    float* h0      = ws;                           // 2.56M
    float* partial = ws + 2560000;                 // NEB*100 = 156.4K
    float* ebar    = ws + 2720000;                 // 128
    unsigned short* A_hi  = (unsigned short*)(ws + 2724000);   // 65536 ushorts
    unsigned short* Efrag = (unsigned short*)(ws + 3000000);   // 16*NVP*8 ushorts

    mega_prep<<<NEB + NAB + NB2BLK, 256, 0, stream>>>(
        E_tag, Efrag, partial, seq, lens, E_ggnn, Afrag, W_ih, W_hh, B2);
    gates_gru<<<dim3(NBL / 128, 3), 256, 0, stream>>>(seq, Afrag, B2, b_ih, b_hh,
                                                      E_ggnn, partial, ebar, h0);
    fuse_kernel<<<NB, 128, 0, stream>>>(seq, lens, nei, wei, s_vec, E_tag, E_glob,
                                        Wout_w, Wout_b, W_w, W3_w, W3_b,
                                        W1_w, W1_b, q1_w, W2_w, W2_b,
                                        G1_w, G1_b, G2_w, G2_b, ebar, h0, A_hi);
    out_gemm_mfma<<<dim3(NVP / 128, NB / 128), 256, 0, stream>>>(A_hi, Efrag, out);
}

// Round 9
// 199.221 us; speedup vs baseline: 1.6170x; 1.0091x over previous
//
#include <hip/hip_runtime.h>
#include <math.h>

namespace {
constexpr int NB = 512;
constexpr int NL = 50;
constexpr int NKN = 32;
constexpr int ND = 100;
constexpr int NV = 100000;
constexpr int NBL = NB * NL;          // 25600
constexpr int NVP = 100096;           // 782*128, padded V for Efrag
constexpr int NEB = 1564;             // prep_E blocks (64 rows each)
constexpr int NAB = 800;              // prep_A blocks (32 rows each)
constexpr int NB2FRAG = 7 * 144 * 16; // 16128 fragment-rows in B2
constexpr int NB2BLK = (NB2FRAG + 255) / 256;  // 63
}

typedef __attribute__((ext_vector_type(8))) short bf16x8;
typedef __attribute__((ext_vector_type(8))) short short8v;
typedef __attribute__((ext_vector_type(4))) float f32x4;

__device__ inline unsigned short f2bf(float x) {
    unsigned u = __float_as_uint(x);
    unsigned r = (u + 0x7fffu + ((u >> 16) & 1u)) >> 16;
    return (unsigned short)r;
}
__device__ inline float bf2f(unsigned short h) {
    return __uint_as_float(((unsigned)h) << 16);
}

// ---------------------------------------------------------------------------
// mega_prep: blockIdx-partitioned prep phases (all independent):
//   [0, NEB)              prep_E : E_tag -> Efrag[kg 0..15][NVP][8] + partial
//   [NEB, NEB+NAB)        prep_A : Afrag[kg 0..47][NBL][8]  (u | v | x segs)
//   [NEB+NAB, +NB2BLK)    prep_B2: gate-interleaved W fragments
// es stride 104 floats: 16B-aligned float4 AND frag-read conflict 8->4-way.
// ---------------------------------------------------------------------------
__global__ __launch_bounds__(256) void mega_prep(
    const float* __restrict__ E_tag, unsigned short* __restrict__ Efrag,
    float* __restrict__ partial,          // [NEB][100] coalesced per block
    const int* __restrict__ seq, const int* __restrict__ lens,
    const float* __restrict__ E_ggnn, unsigned short* __restrict__ Afrag,
    const float* __restrict__ W_ih, const float* __restrict__ W_hh,
    unsigned short* __restrict__ B2)
{
    __shared__ __align__(16) char shbuf[26656];
    const int tid = threadIdx.x;
    const int blk = blockIdx.x;

    if (blk < NEB) {
        // ---------------- prep_E ----------------
        float (*es)[104] = (float(*)[104])shbuf;
        const int v0 = blk * 64;
        for (int idx = tid; idx < 1600; idx += 256) {
            size_t base = (size_t)v0 * 100 + (size_t)idx * 4;
            float4 e = make_float4(0.f, 0.f, 0.f, 0.f);
            if (base + 3 < (size_t)NV * ND) e = *(const float4*)(E_tag + base);
            int row = idx / 25, c4 = (idx - row * 25) * 4;
            *(float4*)&es[row][c4] = e;
        }
        __syncthreads();

        if (tid < ND) {
            float a = 0.f;
#pragma unroll 8
            for (int rr = 0; rr < 64; ++rr) a += es[rr][tid];
            partial[(size_t)blk * ND + tid] = a;     // coalesced 400B
        }
        for (int idx = tid; idx < 16 * 64; idx += 256) {
            int kg = idx >> 6, vloc = idx & 63;
            short8v o;
#pragma unroll
            for (int j = 0; j < 8; ++j) {
                int k = kg * 8 + j;
                o[j] = (short)((k < ND) ? f2bf(es[vloc][k]) : 0);
            }
            *(short8v*)(Efrag + ((size_t)kg * NVP + v0 + vloc) * 8) = o;
        }
    } else if (blk < NEB + NAB) {
        // ---------------- prep_A ----------------
        float (*xs)[100] = (float(*)[100])shbuf;
        float* eo_s = (float*)(shbuf + 13600);
        float* ei_s = eo_s + 34;
        const int r0 = (blk - NEB) * 32;

        for (int idx = tid; idx < 34 * 25; idx += 256) {
            int row = idx / 25, qq = idx - row * 25;
            int rg = r0 - 1 + row;
            rg = rg < 0 ? 0 : (rg >= NBL ? NBL - 1 : rg);
            float4 e = *(const float4*)(E_ggnn + (size_t)seq[rg] * ND + 4 * qq);
            xs[row][4 * qq]     = e.x;
            xs[row][4 * qq + 1] = e.y;
            xs[row][4 * qq + 2] = e.z;
            xs[row][4 * qq + 3] = e.w;
        }
        for (int rr = tid; rr < 34; rr += 256) {
            int rg = r0 - 1 + rr;
            int rc = rg < 0 ? 0 : (rg >= NBL ? NBL - 1 : rg);
            int b = rc / NL, l = rc - b * NL;
            int lenb = lens[b];
            eo_s[rr] = (l < lenb - 1) ? 1.f : 0.f;
            ei_s[rr] = (l >= 1 && l <= lenb - 1) ? 1.f : 0.f;
        }
        __syncthreads();

        for (int idx = tid; idx < 32 * 48; idx += 256) {
            int rloc = idx / 48, kg = idx - rloc * 48;
            int seg = kg >> 4, kk = kg & 15;
            short8v o;
            float eo = eo_s[1 + rloc], ei = ei_s[1 + rloc];
#pragma unroll
            for (int j = 0; j < 8; ++j) {
                int k = kk * 8 + j;
                float v = 0.f;
                if (k < 100) {
                    if (seg == 0)      v = xs[1 + rloc][k] + eo * xs[2 + rloc][k];
                    else if (seg == 1) v = xs[1 + rloc][k] + ei * xs[rloc][k];
                    else               v = xs[1 + rloc][k];
                }
                o[j] = (short)f2bf(v);
            }
            *(short8v*)(Afrag + ((size_t)kg * NBL + r0 + rloc) * 8) = o;
        }
    } else {
        // ---------------- prep_B2 ----------------
        int idx = (blk - NEB - NAB) * 256 + tid;
        if (idx >= NB2FRAG) return;
        int chunk = idx / 2304;
        int rem = idx - chunk * 2304;
        int slot = rem >> 4, c = rem & 15;
        int d = chunk * 16 + c;
        short8v o;
        if (slot < 96) {
            int g = slot >> 5, kg = slot & 31;
            int seg = kg >> 4, kap0 = (kg & 15) * 8;
#pragma unroll
            for (int j = 0; j < 8; ++j) {
                int kap = kap0 + j;
                float v = (kap < 100 && d < 100)
                          ? W_ih[(seg * 100 + kap) * 300 + g * 100 + d] : 0.f;
                o[j] = (short)f2bf(v);
            }
        } else {
            int s2 = slot - 96;
            int g = s2 >> 4, kgp = s2 & 15;
            int kap0 = kgp * 8;
#pragma unroll
            for (int j = 0; j < 8; ++j) {
                int kap = kap0 + j;
                float v = (kap < 100 && d < 100)
                          ? W_hh[kap * 300 + g * 100 + d] : 0.f;
                o[j] = (short)f2bf(v);
            }
        }
        *(short8v*)(B2 + (size_t)idx * 8) = o;
    }
}

// ---------------------------------------------------------------------------
// gates_gru: fused gates-GEMM (MFMA bf16) + GRU epilogue -> h0 directly.
//   blockIdx.y: 0 -> chunks 0..3, 1 -> chunks 4..6 (d-chunks of 16),
//               2 -> ebar reduction (first 100 x-blocks; co-scheduled).
// ---------------------------------------------------------------------------
__global__ __launch_bounds__(256) void gates_gru(
    const int* __restrict__ seq,
    const unsigned short* __restrict__ Afrag,
    const unsigned short* __restrict__ B2,
    const float* __restrict__ b_ih, const float* __restrict__ b_hh,
    const float* __restrict__ E_ggnn,
    const float* __restrict__ partial, float* __restrict__ ebar,
    float* __restrict__ h0)
{
    __shared__ float wsum[4];
    const int tid = threadIdx.x;

    if (blockIdx.y == 2) {
        const int d = blockIdx.x;
        if (d >= ND) return;
        float a = 0.f;
        for (int i = tid; i < NEB; i += 256) a += partial[(size_t)i * ND + d];
#pragma unroll
        for (int off = 32; off > 0; off >>= 1) a += __shfl_down(a, off);
        if ((tid & 63) == 0) wsum[tid >> 6] = a;
        __syncthreads();
        if (tid == 0)
            ebar[d] = (wsum[0] + wsum[1] + wsum[2] + wsum[3]) * (1.f / (float)NV);
        return;
    }

    const int r0  = blockIdx.x * 128;
    const int cc0 = blockIdx.y ? 4 : 0;
    const int cc1 = blockIdx.y ? 7 : 4;
    const int lane = tid & 63;
    const int w = tid >> 6;
    const int q = lane >> 4, c = lane & 15;

    const bf16x8* Ap = (const bf16x8*)Afrag;
    const bf16x8* Bp = (const bf16x8*)B2;

    const int rowA = r0 + w * 32 + c;

    int tok[8];
#pragma unroll
    for (int fm = 0; fm < 2; ++fm)
#pragma unroll
        for (int reg = 0; reg < 4; ++reg)
            tok[fm * 4 + reg] = seq[r0 + w * 32 + fm * 16 + q * 4 + reg];

    for (int cc = cc0; cc < cc1; ++cc) {
        f32x4 acc[2][6];
#pragma unroll
        for (int fm = 0; fm < 2; ++fm)
#pragma unroll
            for (int g = 0; g < 6; ++g) acc[fm][g] = (f32x4)0.f;

        const size_t bbase = (size_t)cc * 144;

#pragma unroll
        for (int st = 0; st < 8; ++st) {
            const int kg = 4 * st + q;
            bf16x8 a0 = Ap[(size_t)kg * NBL + rowA];
            bf16x8 a1 = Ap[(size_t)kg * NBL + rowA + 16];
            bf16x8 b0 = Bp[(bbase + 0 * 32 + kg) * 16 + c];
            bf16x8 b1 = Bp[(bbase + 1 * 32 + kg) * 16 + c];
            bf16x8 b2 = Bp[(bbase + 2 * 32 + kg) * 16 + c];
            acc[0][0] = __builtin_amdgcn_mfma_f32_16x16x32_bf16(a0, b0, acc[0][0], 0, 0, 0);
            acc[1][0] = __builtin_amdgcn_mfma_f32_16x16x32_bf16(a1, b0, acc[1][0], 0, 0, 0);
            acc[0][1] = __builtin_amdgcn_mfma_f32_16x16x32_bf16(a0, b1, acc[0][1], 0, 0, 0);
            acc[1][1] = __builtin_amdgcn_mfma_f32_16x16x32_bf16(a1, b1, acc[1][1], 0, 0, 0);
            acc[0][2] = __builtin_amdgcn_mfma_f32_16x16x32_bf16(a0, b2, acc[0][2], 0, 0, 0);
            acc[1][2] = __builtin_amdgcn_mfma_f32_16x16x32_bf16(a1, b2, acc[1][2], 0, 0, 0);
        }
#pragma unroll
        for (int st = 0; st < 4; ++st) {
            const int kgp = 4 * st + q;
            const int kg  = 32 + kgp;
            bf16x8 a0 = Ap[(size_t)kg * NBL + rowA];
            bf16x8 a1 = Ap[(size_t)kg * NBL + rowA + 16];
            bf16x8 b0 = Bp[(bbase + 96 + 0 * 16 + kgp) * 16 + c];
            bf16x8 b1 = Bp[(bbase + 96 + 1 * 16 + kgp) * 16 + c];
            bf16x8 b2 = Bp[(bbase + 96 + 2 * 16 + kgp) * 16 + c];
            acc[0][3] = __builtin_amdgcn_mfma_f32_16x16x32_bf16(a0, b0, acc[0][3], 0, 0, 0);
            acc[1][3] = __builtin_amdgcn_mfma_f32_16x16x32_bf16(a1, b0, acc[1][3], 0, 0, 0);
            acc[0][4] = __builtin_amdgcn_mfma_f32_16x16x32_bf16(a0, b1, acc[0][4], 0, 0, 0);
            acc[1][4] = __builtin_amdgcn_mfma_f32_16x16x32_bf16(a1, b1, acc[1][4], 0, 0, 0);
            acc[0][5] = __builtin_amdgcn_mfma_f32_16x16x32_bf16(a0, b2, acc[0][5], 0, 0, 0);
            acc[1][5] = __builtin_amdgcn_mfma_f32_16x16x32_bf16(a1, b2, acc[1][5], 0, 0, 0);
        }

        const int d = cc * 16 + c;
        if (d < ND) {
            const float bi0 = b_ih[d], bi1 = b_ih[100 + d], bi2 = b_ih[200 + d];
            const float bh0 = b_hh[d], bh1 = b_hh[100 + d], bh2 = b_hh[200 + d];
#pragma unroll
            for (int fm = 0; fm < 2; ++fm) {
                const int rbase = r0 + w * 32 + fm * 16 + q * 4;
#pragma unroll
                for (int reg = 0; reg < 4; ++reg) {
                    const int row = rbase + reg;
                    float ir = acc[fm][0][reg] + bi0;
                    float iz = acc[fm][1][reg] + bi1;
                    float ig = acc[fm][2][reg] + bi2;
                    float hr = acc[fm][3][reg] + bh0;
                    float hz = acc[fm][4][reg] + bh1;
                    float hg = acc[fm][5][reg] + bh2;
                    float x  = E_ggnn[(size_t)tok[fm * 4 + reg] * ND + d];
                    float rg = 1.f / (1.f + expf(-(ir + hr)));
                    float zg = 1.f / (1.f + expf(-(iz + hz)));
                    float ng = tanhf(ig + rg * hg);
                    h0[(size_t)row * ND + d] = (1.f - zg) * ng + zg * x;
                }
            }
        }
    }
}

// ---------------------------------------------------------------------------
// K45: per-batch fused tail -> sess2 bf16 fragments A[kg 0..15][512][8]
//      Softmaxes wave-parallelized (wave 0 handles both).
// ---------------------------------------------------------------------------
__global__ __launch_bounds__(128) void fuse_kernel(
    const int* __restrict__ seq, const int* __restrict__ lens,
    const int* __restrict__ nei, const float* __restrict__ wei,
    const float* __restrict__ s_vec, const float* __restrict__ E_tag,
    const float* __restrict__ E_glob,
    const float* __restrict__ Wout_w, const float* __restrict__ Wout_b,
    const float* __restrict__ W_w,
    const float* __restrict__ W3_w, const float* __restrict__ W3_b,
    const float* __restrict__ W1_w, const float* __restrict__ W1_b,
    const float* __restrict__ q1_w,
    const float* __restrict__ W2_w, const float* __restrict__ W2_b,
    const float* __restrict__ G1_w, const float* __restrict__ G1_b,
    const float* __restrict__ G2_w, const float* __restrict__ G2_b,
    const float* __restrict__ ebar, const float* __restrict__ h0,
    unsigned short* __restrict__ A_hi)
{
    const int b = blockIdx.x, tid = threadIdx.x;
    __shared__ float t_emb[100], tw[100], twW[100], red[128];
    __shared__ float al[50], att[50];
    __shared__ float g0[100], cc[300], sess_s[100];
    __shared__ float sv[100], hnei[32][100], msg[100], xg[100], xg2[100];
    __shared__ float attg[32], score[32];
    __shared__ float scalars[4];      // 0: bd, 1: sm, 2: mean_b, 3: gate

    int lenb   = lens[b];
    int last_r = b * NL + (lenb - 1);
    int target = seq[last_r];

    if (tid < ND) {
        t_emb[tid] = E_tag[(size_t)target * ND + tid];
        sv[tid]    = s_vec[b * ND + tid];
    }
    __syncthreads();

    if (tid < ND) {
        float a = 0.f;
        for (int k = 0; k < ND; ++k) a += t_emb[k] * W_w[k * ND + tid];
        tw[tid] = a;
    }
    __syncthreads();

    if (tid < ND) {
        float a = 0.f;
        for (int d = 0; d < ND; ++d) a += Wout_w[tid * ND + d] * tw[d];
        twW[tid] = a;
    }
    red[tid] = (tid < ND) ? Wout_b[tid] * tw[tid] : 0.f;
    __syncthreads();
    for (int s = 64; s > 0; s >>= 1) { if (tid < s) red[tid] += red[tid + s]; __syncthreads(); }
    if (tid == 0) scalars[0] = red[0];
    __syncthreads();

    if (tid < NL) {
        const float* hr = h0 + (size_t)(b * NL + tid) * ND;
        float a = scalars[0];
        for (int k = 0; k < ND; ++k) a += hr[k] * twW[k];
        al[tid] = a;
    }
    __syncthreads();

    // wave-parallel softmax over 50 logits (unmasked, matches ref)
    if (tid < 64) {
        float v = (tid < NL) ? al[tid] : -1e30f;
        float m = v;
#pragma unroll
        for (int off = 32; off > 0; off >>= 1) m = fmaxf(m, __shfl_xor(m, off));
        float e = (tid < NL) ? expf(v - m) : 0.f;
        float s = e;
#pragma unroll
        for (int off = 32; off > 0; off >>= 1) s += __shfl_xor(s, off);
        float a = e / s;
        if (tid < NL) att[tid] = a;
        float sm = (tid < lenb) ? a : 0.f;
#pragma unroll
        for (int off = 32; off > 0; off >>= 1) sm += __shfl_xor(sm, off);
        if (tid == 0) scalars[1] = sm;
    }
    __syncthreads();

    if (tid < ND) {
        float a = 0.f;
        for (int l = 0; l < lenb; ++l) a += att[l] * h0[(size_t)(b * NL + l) * ND + tid];
        g0[tid] = a;
    }
    __syncthreads();
    if (tid < ND) {
        float hg = 0.f, hl = 0.f;
        const float* hlast = h0 + (size_t)last_r * ND;
        for (int k = 0; k < ND; ++k) {
            float w = Wout_w[k * ND + tid];
            hg += g0[k] * w;
            hl += hlast[k] * w;
        }
        cc[tid]        = hg + scalars[1] * Wout_b[tid];
        cc[100 + tid]  = hl + Wout_b[tid];
        cc[200 + tid]  = t_emb[tid];
    }
    __syncthreads();

    if (tid < ND) {
        float a = W3_b[tid];
        for (int j = 0; j < 300; ++j) a += cc[j] * W3_w[j * ND + tid];
        sess_s[tid] = tanhf(a);
    }
    __syncthreads();
    red[tid] = (tid < ND) ? sess_s[tid] * ebar[tid] : 0.f;
    __syncthreads();
    for (int s = 64; s > 0; s >>= 1) { if (tid < s) red[tid] += red[tid + s]; __syncthreads(); }
    if (tid == 0) scalars[2] = red[0];
    __syncthreads();

    // ---- global encoder ----
    for (int idx = tid; idx < NKN * ND; idx += 128) {
        int k = idx / ND, d = idx - k * ND;
        hnei[k][d] = E_glob[(size_t)nei[b * NKN + k] * ND + d];
    }
    __syncthreads();

    {
        const int wv = tid >> 6, lane = tid & 63;
        for (int k2 = 0; k2 < NKN / 2; ++k2) {
            int k = k2 * 2 + wv;
            float p = 0.f;
            if (lane < 50) {
                float wk = wei[b * NKN + k];
                float a0 = W1_b[lane]      + wk * W1_w[100 * ND + lane];
                float a1 = W1_b[lane + 50] + wk * W1_w[100 * ND + lane + 50];
                for (int j = 0; j < ND; ++j) {
                    float t = hnei[k][j] * sv[j];
                    a0 += t * W1_w[j * ND + lane];
                    a1 += t * W1_w[j * ND + lane + 50];
                }
                p = tanhf(a0) * q1_w[lane] + tanhf(a1) * q1_w[lane + 50];
            }
            for (int off = 32; off > 0; off >>= 1) p += __shfl_down(p, off);
            if (lane == 0) score[k] = p;
        }
    }
    __syncthreads();

    // wave-parallel softmax over 32 neighbor scores
    if (tid < 64) {
        float v = (tid < NKN) ? score[tid] : -1e30f;
        float m = v;
#pragma unroll
        for (int off = 32; off > 0; off >>= 1) m = fmaxf(m, __shfl_xor(m, off));
        float e = (tid < NKN) ? expf(v - m) : 0.f;
        float s = e;
#pragma unroll
        for (int off = 32; off > 0; off >>= 1) s += __shfl_xor(s, off);
        if (tid < NKN) attg[tid] = e / s;
    }
    __syncthreads();

    if (tid < ND) {
        float a = 0.f;
        for (int k = 0; k < NKN; ++k) a += attg[k] * hnei[k][tid];
        msg[tid] = a;
        xg[tid]  = E_glob[(size_t)target * ND + tid];
    }
    __syncthreads();
    if (tid < ND) {
        float a = W2_b[tid];
        for (int j = 0; j < ND; ++j) a += xg[j]  * W2_w[j * ND + tid];
        for (int j = 0; j < ND; ++j) a += msg[j] * W2_w[(100 + j) * ND + tid];
        xg2[tid] = fmaxf(a, 0.f);
    }
    __syncthreads();
    const float SCALE = (float)(1.0 - 49.0 / 50.0);
    if (tid < ND) {
        float a = W2_b[tid];
        for (int j = 0; j < ND; ++j) a += xg2[j] * W2_w[j * ND + tid];
        for (int j = 0; j < ND; ++j) a += msg[j] * W2_w[(100 + j) * ND + tid];
        xg[tid] = fmaxf(a, 0.f) * SCALE;
    }
    __syncthreads();

    if (tid < ND) {
        float a = G1_b[tid] + scalars[2] * G1_w[tid];
        for (int j = 0; j < ND; ++j) a += xg[j] * G1_w[(1 + j) * ND + tid];
        red[tid] = tanhf(a) * G2_w[tid];
    } else red[tid] = 0.f;
    __syncthreads();
    for (int s = 64; s > 0; s >>= 1) { if (tid < s) red[tid] += red[tid + s]; __syncthreads(); }
    if (tid == 0) scalars[3] = 1.f / (1.f + expf(-(red[0] + G2_b[0])));
    __syncthreads();

    {
        float val = 0.f;
        if (tid < ND) {
            float g = scalars[3];
            val = g * xg[tid] + (1.f - g) * scalars[2];
        }
        int kgrp = tid >> 3, j = tid & 7;
        A_hi[kgrp * 4096 + b * 8 + j] = f2bf(val);
    }
}

// ---------------------------------------------------------------------------
// K6: out = sess2 @ E_tag^T, streaming MFMA: no LDS, frags from global.
// ---------------------------------------------------------------------------
__global__ __launch_bounds__(256) void out_gemm_mfma(
    const unsigned short* __restrict__ A_hi,
    const unsigned short* __restrict__ Efrag,
    float* __restrict__ out)
{
    const int tid = threadIdx.x;
    const int v0  = blockIdx.x * 128;
    const int b0  = blockIdx.y * 128;
    const int lane = tid & 63;
    const int wv = tid >> 6;
    const int wm = wv >> 1, wn = wv & 1;
    const int q = lane >> 4, c = lane & 15;

    f32x4 acc[4][4];
#pragma unroll
    for (int fm = 0; fm < 4; ++fm)
#pragma unroll
        for (int fn = 0; fn < 4; ++fn) acc[fm][fn] = (f32x4)0.f;

    const bf16x8* Ah = (const bf16x8*)A_hi;
    const bf16x8* Ef = (const bf16x8*)Efrag;

#pragma unroll
    for (int s = 0; s < 4; ++s) {
        const int kg = 4 * s + q;
        bf16x8 a[4], b[4];
#pragma unroll
        for (int fm = 0; fm < 4; ++fm)
            a[fm] = Ah[kg * 512 + b0 + wm * 64 + fm * 16 + c];
#pragma unroll
        for (int fn = 0; fn < 4; ++fn)
            b[fn] = Ef[(size_t)kg * NVP + v0 + wn * 64 + fn * 16 + c];
#pragma unroll
        for (int fm = 0; fm < 4; ++fm)
#pragma unroll
            for (int fn = 0; fn < 4; ++fn)
                acc[fm][fn] = __builtin_amdgcn_mfma_f32_16x16x32_bf16(
                    a[fm], b[fn], acc[fm][fn], 0, 0, 0);
    }

#pragma unroll
    for (int fm = 0; fm < 4; ++fm) {
        int row_base = b0 + wm * 64 + fm * 16 + q * 4;
#pragma unroll
        for (int fn = 0; fn < 4; ++fn) {
            int col = v0 + wn * 64 + fn * 16 + c;
            if (col < NV) {
#pragma unroll
                for (int r = 0; r < 4; ++r)
                    out[(size_t)(row_base + r) * NV + col] = acc[fm][fn][r];
            }
        }
    }
}

// ---------------------------------------------------------------------------
extern "C" void kernel_launch(void* const* d_in, const int* in_sizes, int n_in,
                              void* d_out, int out_size, void* d_ws, size_t ws_size,
                              hipStream_t stream)
{
    const int*   seq    = (const int*)  d_in[0];
    const int*   lens   = (const int*)  d_in[1];
    const int*   nei    = (const int*)  d_in[2];
    const float* wei    = (const float*)d_in[3];
    const float* s_vec  = (const float*)d_in[4];
    const float* E_tag  = (const float*)d_in[5];
    const float* E_ggnn = (const float*)d_in[6];
    const float* E_glob = (const float*)d_in[7];
    const float* W_ih   = (const float*)d_in[8];
    const float* b_ih   = (const float*)d_in[9];
    const float* W_hh   = (const float*)d_in[10];
    const float* b_hh   = (const float*)d_in[11];
    const float* Wout_w = (const float*)d_in[12];
    const float* Wout_b = (const float*)d_in[13];
    const float* W_w    = (const float*)d_in[14];
    const float* W3_w   = (const float*)d_in[15];
    const float* W3_b   = (const float*)d_in[16];
    const float* W1_w   = (const float*)d_in[17];
    const float* W1_b   = (const float*)d_in[18];
    const float* q1_w   = (const float*)d_in[19];
    const float* W2_w   = (const float*)d_in[20];
    const float* W2_b   = (const float*)d_in[21];
    const float* G1_w   = (const float*)d_in[22];
    const float* G1_b   = (const float*)d_in[23];
    const float* G2_w   = (const float*)d_in[24];
    const float* G2_b   = (const float*)d_in[25];

    float* out = (float*)d_out;
    // d_out staging (consumed by gates_gru before out_gemm overwrites):
    //   Afrag at float-offset 16M (48*25600*8 ushorts)
    //   B2    at float-offset 21M (16128*8 ushorts)
    unsigned short* Afrag = (unsigned short*)(out + 16000000);
    unsigned short* B2    = (unsigned short*)(out + 21000000);

    // d_ws layout (floats):
    float* ws      = (float*)d_ws;
    float* h0      = ws;                           // 2.56M
    float* partial = ws + 2560000;                 // NEB*100 = 156.4K
    float* ebar    = ws + 2720000;                 // 128
    unsigned short* A_hi  = (unsigned short*)(ws + 2724000);   // 65536 ushorts
    unsigned short* Efrag = (unsigned short*)(ws + 3000000);   // 16*NVP*8 ushorts

    mega_prep<<<NEB + NAB + NB2BLK, 256, 0, stream>>>(
        E_tag, Efrag, partial, seq, lens, E_ggnn, Afrag, W_ih, W_hh, B2);
    gates_gru<<<dim3(NBL / 128, 3), 256, 0, stream>>>(seq, Afrag, B2, b_ih, b_hh,
                                                      E_ggnn, partial, ebar, h0);
    fuse_kernel<<<NB, 128, 0, stream>>>(seq, lens, nei, wei, s_vec, E_tag, E_glob,
                                        Wout_w, Wout_b, W_w, W3_w, W3_b,
                                        W1_w, W1_b, q1_w, W2_w, W2_b,
                                        G1_w, G1_b, G2_w, G2_b, ebar, h0, A_hi);
    out_gemm_mfma<<<dim3(NVP / 128, NB / 128), 256, 0, stream>>>(A_hi, Efrag, out);
}